// Round 19
// baseline (116.027 us; speedup 1.0000x reference)
//
#include <hip/hip_runtime.h>
#include <math.h>

#define BATCH 16
#define NPX 4096            // 64*64
#define CDIM 128
#define CC 116              // conv channels
#define KTAPS 1044          // 9*116

using u16 = unsigned short;
typedef __attribute__((ext_vector_type(8))) short short8;
typedef __attribute__((ext_vector_type(16))) float f32x16;

__device__ __forceinline__ float swishf(float z) {
    return z / (1.f + __expf(-z));
}
__device__ __forceinline__ float bf2f(u16 u) {
    union { unsigned int i; float f; } v; v.i = ((unsigned int)u) << 16; return v.f;
}
__device__ __forceinline__ u16 f2bf(float f) {
    union { float f; unsigned int i; } v; v.f = f;
    unsigned int r = v.i + 0x7fffu + ((v.i >> 16) & 1u);
    return (u16)(r >> 16);
}

// ---------------- 4-qubit circuit ----------------
__device__ void run_circuit(const float* ang, const float* th, float* z) {
    float ar[16], ai[16];
#pragma unroll
    for (int k = 0; k < 16; ++k) { ar[k] = 0.f; ai[k] = 0.f; }
    ar[0] = 1.f;
#pragma unroll
    for (int pass = 0; pass < 2; ++pass) {
        const float* a = pass ? th : ang;
#pragma unroll
        for (int w = 0; w < 4; ++w) {
            float half = 0.5f * a[w];
            float cth = cosf(half), sth = sinf(half);
            int m = 1 << (3 - w);
#pragma unroll
            for (int k = 0; k < 16; ++k) {
                if (k & m) continue;
                int k2 = k | m;
                float r0 = ar[k], i0 = ai[k], r1 = ar[k2], i1 = ai[k2];
                ar[k]  = cth * r0 + sth * i1;
                ai[k]  = cth * i0 - sth * r1;
                ar[k2] = sth * i0 + cth * r1;
                ai[k2] = -sth * r0 + cth * i1;
            }
        }
    }
#pragma unroll
    for (int e = 0; e < 4; ++e) {
        const int cwi[4] = {0, 1, 2, 3};
        const int twi[4] = {1, 2, 3, 0};
        int mc = 1 << (3 - cwi[e]), mt = 1 << (3 - twi[e]);
#pragma unroll
        for (int k = 0; k < 16; ++k) {
            if ((k & mc) && !(k & mt)) {
                int k2 = k | mt;
                float tr = ar[k]; ar[k] = ar[k2]; ar[k2] = tr;
                float ti = ai[k]; ai[k] = ai[k2]; ai[k2] = ti;
            }
        }
    }
    float zz[4] = {0.f, 0.f, 0.f, 0.f};
#pragma unroll
    for (int k = 0; k < 16; ++k) {
        float p = ar[k] * ar[k] + ai[k] * ai[k];
#pragma unroll
        for (int w = 0; w < 4; ++w) zz[w] += ((k >> (3 - w)) & 1) ? -p : p;
    }
#pragma unroll
    for (int w = 0; w < 4; ++w) z[w] = zz[w];
}

// -------- merged: pooled partials (bx<128) | csum zero (128..143) | time MLP
//          (144..159) | weight-standardize+pack (160..415) --------
__global__ void k_misc(const float* __restrict__ x, float* __restrict__ part,
                       float* __restrict__ csums,
                       const float* __restrict__ te, const float* __restrict__ W,
                       const float* __restrict__ tb, float* __restrict__ t,
                       const float* __restrict__ K0, const float* __restrict__ K1,
                       u16* __restrict__ kqp0, u16* __restrict__ kqp1) {
    const int bx = blockIdx.x, tid = threadIdx.x;
    __shared__ float red[12][256];
    __shared__ float se[512];
    __shared__ float rs[256], rss[256], mb[2];
    if (bx < 128) {
        const int b = bx >> 3, seg = bx & 7;
        float s[12];
#pragma unroll
        for (int c = 0; c < 12; ++c) s[c] = 0.f;
        const float* xb = x + (size_t)(b * 4096 + seg * 512) * CDIM;
#pragma unroll
        for (int i = 0; i < 2; ++i) {
            const float4* p = (const float4*)(xb + (size_t)(tid + i * 256) * CDIM);
            float4 v0 = p[0], v1 = p[1], v2 = p[2];
            s[0] += v0.x; s[1] += v0.y; s[2] += v0.z; s[3] += v0.w;
            s[4] += v1.x; s[5] += v1.y; s[6] += v1.z; s[7] += v1.w;
            s[8] += v2.x; s[9] += v2.y; s[10] += v2.z; s[11] += v2.w;
        }
#pragma unroll
        for (int c = 0; c < 12; ++c) red[c][tid] = s[c];
        __syncthreads();
        for (int st = 128; st > 0; st >>= 1) {
            if (tid < st) {
#pragma unroll
                for (int c = 0; c < 12; ++c) red[c][tid] += red[c][tid + st];
            }
            __syncthreads();
        }
        if (tid < 12) part[bx * 12 + tid] = red[tid][0];
        return;
    }
    if (bx < 144) {
        int i = (bx - 128) * 256 + tid;
        csums[i * 2] = 0.f;
        csums[i * 2 + 1] = 0.f;
        return;
    }
    if (bx < 160) {
        const int b = bx - 144;
        for (int k = tid; k < 512; k += 256) se[k] = swishf(te[b * 512 + k]);
        __syncthreads();
        float acc = tb[tid];
        for (int k = 0; k < 512; ++k) acc += se[k] * W[k * 256 + tid];
        t[b * 256 + tid] = acc;
        return;
    }
    const int r = bx - 160;
    const float* K = (r >> 7) ? K1 : K0;
    u16* kqp = (r >> 7) ? kqp1 : kqp0;
    const int o = r & 127;
    float s = 0.f, ss = 0.f;
    if (o < CC) {
        for (int idx = tid; idx < KTAPS; idx += 256) {
            float v = K[(size_t)idx * CC + o];
            s += v; ss += v * v;
        }
    }
    rs[tid] = s; rss[tid] = ss;
    __syncthreads();
    for (int st = 128; st > 0; st >>= 1) {
        if (tid < st) { rs[tid] += rs[tid + st]; rss[tid] += rss[tid + st]; }
        __syncthreads();
    }
    if (tid == 0) {
        float m = rs[0] * (1.f / KTAPS);
        float var = rss[0] * (1.f / KTAPS) - m * m;
        mb[0] = m;
        mb[1] = rsqrtf(var + 1e-5f);
    }
    __syncthreads();
    float m = mb[0], inv = mb[1];
    for (int idx = tid; idx < 1152; idx += 256) {
        int tap = idx >> 7, ic = idx & 127;
        float v = 0.f;
        if (o < CC && ic < CC) v = (K[((size_t)tap * CC + ic) * CC + o] - m) * inv;
        int step = tap * 8 + (ic >> 4);
        int lane2 = ((ic >> 3) & 1) * 32 + (o & 31);
        int j = ic & 7;
        kqp[(size_t)(step * 4 + (o >> 5)) * 512 + lane2 * 8 + j] = f2bf(v);
    }
}

// ---------------- MFMA 32x32x16 implicit-GEMM conv, 128px x 128oc, 512 threads ----
// R17 measured-best skeleton; changes this round: (1) NO per-step s_setprio (m190:
// negative on lockstep barrier-synced grids), (2) phase-C loads issued before
// WRITECHUNK(rr) so both load groups are in flight together (counted vmcnt).
template <int MODE>
__launch_bounds__(512, 2)
__global__ void k_conv(const void* __restrict__ inp, const float* __restrict__ Acoef,
                       const float* __restrict__ Bcoef, const u16* __restrict__ kqp,
                       const float* __restrict__ bias, u16* __restrict__ outp,
                       float* __restrict__ csum) {
    __shared__ u16 As[32768];      // 64KB: 4 rows x 64 px x 128 ch (then repack)
    __shared__ float cfA[132], cfB[132];   // MODE1 coefs, stride-33 (conflict-free)
    const int hb = blockIdx.x, b = blockIdx.y;
    const int hp = ((hb & 7) << 2) | (hb >> 3);   // XCD band swizzle (bijective 0..31)
    const int h0 = hp * 2;
    const int tid = threadIdx.x, lane = tid & 63, wid = tid >> 6;
    const int wm = wid & 1, wn = wid >> 1;
    const int l31 = lane & 31;
    const int rr = tid >> 8, pp = (tid >> 2) & 63, ck = tid & 3;
    const int swz = (pp & 15) << 4;

    if (MODE == 1) {
        if (tid < 128) {
            int ckk = tid >> 5, ee = tid & 31;
            float a = 0.f, bbv = 0.f;
            if (tid < CC) {
                a = Acoef[b * 128 + 12 + tid];
                bbv = Bcoef[b * 128 + 12 + tid];
            }
            cfA[ckk * 33 + ee] = a;
            cfB[ckk * 33 + ee] = bbv;
        }
        __syncthreads();               // cf visible; before any staging loads issue
    }

    float fv[32]; short8 sv[4];
    float fv2[32]; short8 sv2[4];

#define LOADCHUNK(r, fvv, svv, val) do { \
    const int hi_ = h0 + (r) - 1; \
    val = (hi_ >= 0 && hi_ < 64); \
    if (val) { \
        const size_t px_ = (size_t)((b * 64 + hi_) * 64 + pp); \
        if (MODE == 0) { \
            const float* sp_ = (const float*)inp + px_ * 128 + 12 + ck * 32; \
            if (ck < 3) { \
                _Pragma("unroll") for (int j = 0; j < 8; ++j) *(float4*)&fvv[j * 4] = ((const float4*)sp_)[j]; \
            } else { \
                _Pragma("unroll") for (int j = 0; j < 5; ++j) *(float4*)&fvv[j * 4] = ((const float4*)sp_)[j]; \
                _Pragma("unroll") for (int e = 20; e < 32; ++e) fvv[e] = 0.f; \
            } \
        } else { \
            const u16* sp_ = (const u16*)inp + px_ * 128 + ck * 32; \
            _Pragma("unroll") for (int k = 0; k < 4; ++k) svv[k] = ((const short8*)sp_)[k]; \
        } \
    } \
} while (0)

#define WRITECHUNK(r, fvv, svv, val) do { \
    u16 t_[32]; \
    if (val) { \
        if (MODE == 0) { \
            _Pragma("unroll") for (int e = 0; e < 32; ++e) t_[e] = f2bf(fvv[e]); \
        } else { \
            _Pragma("unroll") for (int e = 0; e < 32; ++e) { \
                int c_ = ck * 32 + e; \
                float f_ = bf2f((u16)svv[e >> 3][e & 7]); \
                float w_ = swishf(f_ * cfA[ck * 33 + e] + cfB[ck * 33 + e]); \
                t_[e] = (c_ < CC) ? f2bf(w_) : (u16)0; \
            } \
        } \
    } else { \
        _Pragma("unroll") for (int e = 0; e < 32; ++e) t_[e] = 0; \
    } \
    char* rb_ = (char*)As + ((r) * 64 + pp) * 256; \
    _Pragma("unroll") for (int k = 0; k < 4; ++k) \
        *(short8*)(rb_ + ((ck * 64 + k * 16) ^ swz)) = *(const short8*)&t_[k * 8]; \
} while (0)

    bool valA, valC;
    LOADCHUNK(rr, fv, sv, valA);
    LOADCHUNK(2 + rr, fv2, sv2, valC);    // in flight alongside rr's loads
    WRITECHUNK(rr, fv, sv, valA);         // waits vmcnt(8): rr's data only

    // B prologue: ring depth 4, one 32-oc fragment per wave per step
    const u16* bp = kqp + (size_t)wn * 512 + (size_t)lane * 8;
    short8 breg[4];
#pragma unroll
    for (int s = 0; s < 4; ++s) breg[s] = *(const short8*)(bp + ((size_t)s << 11));

    // A-frag addressing (static arrays, compile-time indexed)
    const int kh16 = (lane >> 5) << 4;
    int coloff[2][3], colswz[2][3];
#pragma unroll
    for (int mf = 0; mf < 2; ++mf)
#pragma unroll
        for (int q = 0; q < 3; ++q) {
            int c = mf * 32 + l31 + q - 1;
            int cc = c < 0 ? 0 : (c > 63 ? 63 : c);
            coloff[mf][q] = cc << 7;
            colswz[mf][q] = (cc & 15) << 4;
        }
    const bool e0 = (l31 == 0), e1 = (l31 == 31);
    const short8 zero8 = {0, 0, 0, 0, 0, 0, 0, 0};
    const int rowb = wm * 8192;

    asm volatile("s_waitcnt lgkmcnt(0)" ::: "memory");
    __builtin_amdgcn_s_barrier();         // raw: phase-C vmcnt stays outstanding

    f32x16 acc[2];
#pragma unroll
    for (int mf = 0; mf < 2; ++mf)
#pragma unroll
        for (int r = 0; r < 16; ++r) acc[mf][r] = 0.f;

#define AREAD(dst, s) do { \
    const int tap_ = (s) >> 3, p_ = tap_ / 3, q_ = tap_ % 3; \
    const int chb_ = ((s) & 7) << 5; \
    dst[0] = *(const short8*)&As[rowb + p_ * 8192 + coloff[0][q_] + (((chb_ + kh16) ^ colswz[0][q_]) >> 1)]; \
    dst[1] = *(const short8*)&As[rowb + p_ * 8192 + coloff[1][q_] + (((chb_ + kh16) ^ colswz[1][q_]) >> 1)]; \
} while (0)

#define STEP(s, base, lim) do { \
    const int cur_ = ((s) - (base)) & 1, nxt_ = cur_ ^ 1; \
    if ((s) + 1 < (lim)) AREAD(afr[nxt_], (s) + 1); \
    const int q_ = ((s) >> 3) % 3; \
    short8 a0_ = afr[cur_][0], a1_ = afr[cur_][1]; \
    if (q_ == 0) a0_ = e0 ? zero8 : a0_; \
    if (q_ == 2) a1_ = e1 ? zero8 : a1_; \
    acc[0] = __builtin_amdgcn_mfma_f32_32x32x16_bf16(a0_, breg[(s) & 3], acc[0], 0, 0, 0); \
    acc[1] = __builtin_amdgcn_mfma_f32_32x32x16_bf16(a1_, breg[(s) & 3], acc[1], 0, 0, 0); \
    if ((s) + 4 < 72) breg[(s) & 3] = *(const short8*)(bp + ((size_t)((s) + 4) << 11)); \
} while (0)

    short8 afr[2][2];
    AREAD(afr[0], 0);
#pragma unroll
    for (int s = 0; s < 24; ++s) STEP(s, 0, 24);     // p=0 taps (LDS rows wm..wm+1)

    WRITECHUNK(2 + rr, fv2, sv2, valC);              // loads arrived during p=0
    asm volatile("s_waitcnt lgkmcnt(0)" ::: "memory");
    __builtin_amdgcn_s_barrier();

    AREAD(afr[0], 24);
#pragma unroll
    for (int s = 24; s < 72; ++s) STEP(s, 24, 72);   // p=1,2 taps

    // ---- epilogue: bias, csum, LDS repack -> coalesced bf16 stores ----
    const int oc = wn * 32 + l31;
    const float bv = (oc < CC) ? bias[oc] : 0.f;
    float cs = 0.f, cq = 0.f;
    const int rbase = (lane >> 5) << 2;

    asm volatile("s_waitcnt lgkmcnt(0)" ::: "memory");
    __builtin_amdgcn_s_barrier();                    // all AREADs done; reuse As
#pragma unroll
    for (int mf = 0; mf < 2; ++mf) {
#pragma unroll
        for (int r = 0; r < 16; ++r) {
            int drow = (r & 3) + ((r >> 2) << 3) + rbase;
            int flat = wm * 64 + mf * 32 + drow;     // 0..127 within tile
            float v = acc[mf][r] + bv;
            As[flat * 128 + oc] = f2bf(v);
            cs += v;
            cq += v * v;
        }
    }
    asm volatile("s_waitcnt lgkmcnt(0)" ::: "memory");
    __builtin_amdgcn_s_barrier();
    {
        size_t obase = (size_t)(b * 4096 + h0 * 64) * 128;
#pragma unroll
        for (int k = 0; k < 4; ++k)
            *(short8*)&outp[obase + k * 4096 + tid * 8] = *(const short8*)&As[k * 4096 + tid * 8];
    }
    cs += __shfl_xor(cs, 32);
    cq += __shfl_xor(cq, 32);
    if (lane < 32) {
        atomicAdd(&csum[(b * 128 + oc) * 2], cs);
        atomicAdd(&csum[(b * 128 + oc) * 2 + 1], cq);
    }
#undef LOADCHUNK
#undef WRITECHUNK
#undef AREAD
#undef STEP
}

// ---------------- fused: pooled + circuit1 + GN0 stats + FiLM coefs + circuit 2 ----
__global__ void k_mid0(const float* __restrict__ part, const float* __restrict__ csum,
                       const float* __restrict__ t, const float* __restrict__ gs,
                       const float* __restrict__ gb, const float* __restrict__ qp,
                       float* __restrict__ A, float* __restrict__ Bc,
                       float* __restrict__ y2) {
    __shared__ float pooled_s[192], y1s[192], sst[128][2];
    int tid = threadIdx.x;
    if (tid < 192) {
        int b = tid / 12, c = tid % 12;
        float s = 0.f;
#pragma unroll
        for (int k = 0; k < 8; ++k) s += part[(b * 8 + k) * 12 + c];
        pooled_s[tid] = s * (1.f / 4096.f);
    }
    __syncthreads();
    if (tid < 48) {
        int b = tid / 3, g = tid % 3;
        float z[4];
        run_circuit(&pooled_s[b * 12 + g * 4], qp + g * 4, z);
#pragma unroll
        for (int w = 0; w < 4; ++w) y1s[b * 12 + g * 4 + w] = z[w];
    }
    __syncthreads();
    if (tid < 128) {
        int b = tid >> 3, g = tid & 7;
        float S = 0.f, SS = 0.f;
#pragma unroll
        for (int e = 0; e < 16; ++e) {
            int orig = g * 16 + e;
            if (orig >= 12) {
                int cc = orig - 12;
                S += csum[(b * 128 + cc) * 2];
                SS += csum[(b * 128 + cc) * 2 + 1];
            }
        }
        if (g == 0) {
#pragma unroll
            for (int c = 0; c < 12; ++c) {
                float v = y1s[b * 12 + c];
                S += 4096.f * v;
                SS += 4096.f * v * v;
            }
        }
        float mu = S * (1.f / 65536.f);
        float var = SS * (1.f / 65536.f) - mu * mu;
        sst[tid][0] = mu;
        sst[tid][1] = rsqrtf(var + 1e-6f);
    }
    __syncthreads();
    for (int i = tid; i < 2048; i += 256) {
        int b = i >> 7, c = i & 127, g = c >> 4;
        float mu = sst[b * 8 + g][0], isd = sst[b * 8 + g][1];
        float sc = t[b * 256 + c], sh = t[b * 256 + 128 + c];
        float a = isd * gs[c];
        float bb = gb[c] - mu * a;
        A[i] = a * (1.f + sc);
        Bc[i] = bb * (1.f + sc) + sh;
    }
    if (tid < 48) {
        int b = tid / 3, gq = tid % 3;
        float pin[4], z[4];
        float mu = sst[b * 8][0], isd = sst[b * 8][1];
#pragma unroll
        for (int w = 0; w < 4; ++w) {
            int c = gq * 4 + w;
            float a = isd * gs[c];
            float bb = gb[c] - mu * a;
            float sc = t[b * 256 + c], sh = t[b * 256 + 128 + c];
            float v = y1s[b * 12 + c];
            pin[w] = swishf(v * (a * (1.f + sc)) + (bb * (1.f + sc) + sh));
        }
        run_circuit(pin, qp + gq * 4, z);
#pragma unroll
        for (int w = 0; w < 4; ++w) y2[b * 12 + gq * 4 + w] = z[w];
    }
}

// ---------------- fused: GN1 stats + coefs + quantum output ----------------
__global__ void k_mid1(const float* __restrict__ csum, const float* __restrict__ y2,
                       const float* __restrict__ gs, const float* __restrict__ gb,
                       float* __restrict__ A2, float* __restrict__ B2,
                       float* __restrict__ oq) {
    __shared__ float sst[128][2];
    int tid = threadIdx.x;
    if (tid < 128) {
        int b = tid >> 3, g = tid & 7;
        float S = 0.f, SS = 0.f;
#pragma unroll
        for (int e = 0; e < 16; ++e) {
            int orig = g * 16 + e;
            if (orig >= 12) {
                int cc = orig - 12;
                S += csum[(b * 128 + cc) * 2];
                SS += csum[(b * 128 + cc) * 2 + 1];
            }
        }
        if (g == 0) {
#pragma unroll
            for (int c = 0; c < 12; ++c) {
                float v = y2[b * 12 + c];
                S += 4096.f * v;
                SS += 4096.f * v * v;
            }
        }
        float mu = S * (1.f / 65536.f);
        float var = SS * (1.f / 65536.f) - mu * mu;
        sst[tid][0] = mu;
        sst[tid][1] = rsqrtf(var + 1e-6f);
    }
    __syncthreads();
    for (int i = tid; i < 2048; i += 256) {
        int b = i >> 7, c = i & 127, g = c >> 4;
        float mu = sst[b * 8 + g][0], isd = sst[b * 8 + g][1];
        float a = isd * gs[c];
        A2[i] = a;
        B2[i] = gb[c] - mu * a;
    }
    if (tid < 192) {
        int b = tid / 12, c = tid % 12;
        float mu = sst[b * 8][0], isd = sst[b * 8][1];
        float a = isd * gs[c];
        float bb = gb[c] - mu * a;
        oq[b * 12 + c] = swishf(y2[b * 12 + c] * a + bb);
    }
}

// ---------------- out = x + swish(A2*v + B2) ----------------
__global__ void k_final(const float* __restrict__ x, const u16* __restrict__ co,
                        const float* __restrict__ A2, const float* __restrict__ B2,
                        const float* __restrict__ oq, float* __restrict__ outp) {
    const int t = blockIdx.x, b = blockIdx.y;
    const int seg = t >> 6, hraw = t & 63;
    const int h = ((hraw & 7) << 3) | (hraw >> 3);
    const int tid = threadIdx.x;
    const size_t px = (size_t)(b * 64 + h) * 64 + seg * 8 + (tid >> 5);
    const int c4 = tid & 31, c = c4 * 4;
    float4 xv = *(const float4*)(x + px * CDIM + c);
    float4 r;
    if (c4 < 3) {
        const float* q = oq + b * 12 + c;
        r.x = xv.x + q[0]; r.y = xv.y + q[1]; r.z = xv.z + q[2]; r.w = xv.w + q[3];
    } else {
        int cc = c - 12;
        const u16* hp = co + px * 128 + cc;
        float4 a = *(const float4*)(A2 + b * 128 + c);
        float4 bb = *(const float4*)(B2 + b * 128 + c);
        r.x = xv.x + swishf(bf2f(hp[0]) * a.x + bb.x);
        r.y = xv.y + swishf(bf2f(hp[1]) * a.y + bb.y);
        r.z = xv.z + swishf(bf2f(hp[2]) * a.z + bb.z);
        r.w = xv.w + swishf(bf2f(hp[3]) * a.w + bb.w);
    }
    *(float4*)(outp + px * CDIM + c) = r;
}

extern "C" void kernel_launch(void* const* d_in, const int* in_sizes, int n_in,
                              void* d_out, int out_size, void* d_ws, size_t ws_size,
                              hipStream_t stream) {
    const float* x        = (const float*)d_in[0];
    const float* time_emb = (const float*)d_in[1];
    const float* qparams  = (const float*)d_in[2];
    const float* c0k      = (const float*)d_in[3];
    const float* c0b      = (const float*)d_in[4];
    const float* c1k      = (const float*)d_in[5];
    const float* c1b      = (const float*)d_in[6];
    const float* g0s      = (const float*)d_in[7];
    const float* g0b      = (const float*)d_in[8];
    const float* g1s      = (const float*)d_in[9];
    const float* g1b      = (const float*)d_in[10];
    const float* tw       = (const float*)d_in[11];
    const float* tb       = (const float*)d_in[12];
    float* outp = (float*)d_out;
    float* ws = (float*)d_ws;

    size_t o = 0;
    auto alloc = [&](size_t n) { size_t r = o; o += (n + 15) & ~(size_t)15; return r; };
    float* part   = ws + alloc(1536);
    float* csums  = ws + alloc(8192);            // csum0 | csum1
    float* csum0  = csums;
    float* csum1  = csums + 4096;
    float* t      = ws + alloc(4096);
    float* A      = ws + alloc(2048);
    float* Bc     = ws + alloc(2048);
    float* A2     = ws + alloc(2048);
    float* B2     = ws + alloc(2048);
    float* y2     = ws + alloc(192);
    float* oq     = ws + alloc(192);
    u16* kqp0     = (u16*)(ws + alloc(73728));   // 72*4*512 bf16
    u16* kqp1     = (u16*)(ws + alloc(73728));
    u16* convA    = (u16*)(ws + alloc(4194304)); // [16][4096][128] bf16 (conv0 out)
    u16* convB    = (u16*)(ws + alloc(4194304)); // conv1 out

    k_misc<<<416, 256, 0, stream>>>(x, part, csums, time_emb, tw, tb, t,
                                    c0k, c1k, kqp0, kqp1);

    dim3 cgrid(32, 16);
    k_conv<0><<<cgrid, 512, 0, stream>>>(x, nullptr, nullptr, kqp0, c0b, convA, csum0);
    k_mid0<<<1, 256, 0, stream>>>(part, csum0, t, g0s, g0b, qparams, A, Bc, y2);

    k_conv<1><<<cgrid, 512, 0, stream>>>(convA, A, Bc, kqp1, c1b, convB, csum1);
    k_mid1<<<1, 256, 0, stream>>>(csum1, y2, g1s, g1b, A2, B2, oq);
    k_final<<<dim3(512, 16), 256, 0, stream>>>(x, convB, A2, B2, oq, outp);
}

// Round 20
// 112.299 us; speedup vs baseline: 1.0332x; 1.0332x over previous
//
#include <hip/hip_runtime.h>
#include <math.h>

#define BATCH 16
#define NPX 4096            // 64*64
#define CDIM 128
#define CC 116              // conv channels
#define KTAPS 1044          // 9*116

using u16 = unsigned short;
typedef __attribute__((ext_vector_type(8))) short short8;
typedef __attribute__((ext_vector_type(16))) float f32x16;

__device__ __forceinline__ float swishf(float z) {
    return z / (1.f + __expf(-z));
}
__device__ __forceinline__ float bf2f(u16 u) {
    union { unsigned int i; float f; } v; v.i = ((unsigned int)u) << 16; return v.f;
}
__device__ __forceinline__ u16 f2bf(float f) {
    union { float f; unsigned int i; } v; v.f = f;
    unsigned int r = v.i + 0x7fffu + ((v.i >> 16) & 1u);
    return (u16)(r >> 16);
}

// ---------------- 4-qubit circuit ----------------
__device__ void run_circuit(const float* ang, const float* th, float* z) {
    float ar[16], ai[16];
#pragma unroll
    for (int k = 0; k < 16; ++k) { ar[k] = 0.f; ai[k] = 0.f; }
    ar[0] = 1.f;
#pragma unroll
    for (int pass = 0; pass < 2; ++pass) {
        const float* a = pass ? th : ang;
#pragma unroll
        for (int w = 0; w < 4; ++w) {
            float half = 0.5f * a[w];
            float cth = cosf(half), sth = sinf(half);
            int m = 1 << (3 - w);
#pragma unroll
            for (int k = 0; k < 16; ++k) {
                if (k & m) continue;
                int k2 = k | m;
                float r0 = ar[k], i0 = ai[k], r1 = ar[k2], i1 = ai[k2];
                ar[k]  = cth * r0 + sth * i1;
                ai[k]  = cth * i0 - sth * r1;
                ar[k2] = sth * i0 + cth * r1;
                ai[k2] = -sth * r0 + cth * i1;
            }
        }
    }
#pragma unroll
    for (int e = 0; e < 4; ++e) {
        const int cwi[4] = {0, 1, 2, 3};
        const int twi[4] = {1, 2, 3, 0};
        int mc = 1 << (3 - cwi[e]), mt = 1 << (3 - twi[e]);
#pragma unroll
        for (int k = 0; k < 16; ++k) {
            if ((k & mc) && !(k & mt)) {
                int k2 = k | mt;
                float tr = ar[k]; ar[k] = ar[k2]; ar[k2] = tr;
                float ti = ai[k]; ai[k] = ai[k2]; ai[k2] = ti;
            }
        }
    }
    float zz[4] = {0.f, 0.f, 0.f, 0.f};
#pragma unroll
    for (int k = 0; k < 16; ++k) {
        float p = ar[k] * ar[k] + ai[k] * ai[k];
#pragma unroll
        for (int w = 0; w < 4; ++w) zz[w] += ((k >> (3 - w)) & 1) ? -p : p;
    }
#pragma unroll
    for (int w = 0; w < 4; ++w) z[w] = zz[w];
}

// -------- merged: pooled partials (bx<128) | csum zero (128..143) | time MLP
//          (144..159) | weight-standardize+pack (160..415) --------
__global__ void k_misc(const float* __restrict__ x, float* __restrict__ part,
                       float* __restrict__ csums,
                       const float* __restrict__ te, const float* __restrict__ W,
                       const float* __restrict__ tb, float* __restrict__ t,
                       const float* __restrict__ K0, const float* __restrict__ K1,
                       u16* __restrict__ kqp0, u16* __restrict__ kqp1) {
    const int bx = blockIdx.x, tid = threadIdx.x;
    __shared__ float red[12][256];
    __shared__ float se[512];
    __shared__ float rs[256], rss[256], mb[2];
    if (bx < 128) {
        const int b = bx >> 3, seg = bx & 7;
        float s[12];
#pragma unroll
        for (int c = 0; c < 12; ++c) s[c] = 0.f;
        const float* xb = x + (size_t)(b * 4096 + seg * 512) * CDIM;
#pragma unroll
        for (int i = 0; i < 2; ++i) {
            const float4* p = (const float4*)(xb + (size_t)(tid + i * 256) * CDIM);
            float4 v0 = p[0], v1 = p[1], v2 = p[2];
            s[0] += v0.x; s[1] += v0.y; s[2] += v0.z; s[3] += v0.w;
            s[4] += v1.x; s[5] += v1.y; s[6] += v1.z; s[7] += v1.w;
            s[8] += v2.x; s[9] += v2.y; s[10] += v2.z; s[11] += v2.w;
        }
#pragma unroll
        for (int c = 0; c < 12; ++c) red[c][tid] = s[c];
        __syncthreads();
        for (int st = 128; st > 0; st >>= 1) {
            if (tid < st) {
#pragma unroll
                for (int c = 0; c < 12; ++c) red[c][tid] += red[c][tid + st];
            }
            __syncthreads();
        }
        if (tid < 12) part[bx * 12 + tid] = red[tid][0];
        return;
    }
    if (bx < 144) {
        int i = (bx - 128) * 256 + tid;
        csums[i * 2] = 0.f;
        csums[i * 2 + 1] = 0.f;
        return;
    }
    if (bx < 160) {
        const int b = bx - 144;
        for (int k = tid; k < 512; k += 256) se[k] = swishf(te[b * 512 + k]);
        __syncthreads();
        float acc = tb[tid];
        for (int k = 0; k < 512; ++k) acc += se[k] * W[k * 256 + tid];
        t[b * 256 + tid] = acc;
        return;
    }
    const int r = bx - 160;
    const float* K = (r >> 7) ? K1 : K0;
    u16* kqp = (r >> 7) ? kqp1 : kqp0;
    const int o = r & 127;
    float s = 0.f, ss = 0.f;
    if (o < CC) {
        for (int idx = tid; idx < KTAPS; idx += 256) {
            float v = K[(size_t)idx * CC + o];
            s += v; ss += v * v;
        }
    }
    rs[tid] = s; rss[tid] = ss;
    __syncthreads();
    for (int st = 128; st > 0; st >>= 1) {
        if (tid < st) { rs[tid] += rs[tid + st]; rss[tid] += rss[tid + st]; }
        __syncthreads();
    }
    if (tid == 0) {
        float m = rs[0] * (1.f / KTAPS);
        float var = rss[0] * (1.f / KTAPS) - m * m;
        mb[0] = m;
        mb[1] = rsqrtf(var + 1e-5f);
    }
    __syncthreads();
    float m = mb[0], inv = mb[1];
    for (int idx = tid; idx < 1152; idx += 256) {
        int tap = idx >> 7, ic = idx & 127;
        float v = 0.f;
        if (o < CC && ic < CC) v = (K[((size_t)tap * CC + ic) * CC + o] - m) * inv;
        int step = tap * 8 + (ic >> 4);
        int lane2 = ((ic >> 3) & 1) * 32 + (o & 31);
        int j = ic & 7;
        kqp[(size_t)(step * 4 + (o >> 5)) * 512 + lane2 * 8 + j] = f2bf(v);
    }
}

// ---------------- MFMA 32x32x16 implicit-GEMM conv, 128px x 128oc, 512 threads ----
// R17 measured-best skeleton. MODE 1 additionally computes its own FiLM coefs
// (GN0 stats + time-MLP fold + circuit) in the prologue, hidden under staging
// load latency -- eliminating the k_mid0 kernel. Block hb==0 also emits y2.
template <int MODE>
__launch_bounds__(512, 2)
__global__ void k_conv(const void* __restrict__ inp, const u16* __restrict__ kqp,
                       const float* __restrict__ bias, u16* __restrict__ outp,
                       float* __restrict__ csum,
                       const float* __restrict__ part, const float* __restrict__ csin,
                       const float* __restrict__ t, const float* __restrict__ gs,
                       const float* __restrict__ gb, const float* __restrict__ qp,
                       float* __restrict__ y2out) {
    __shared__ u16 As[32768];      // 64KB: 4 rows x 64 px x 128 ch (then repack)
    __shared__ float cfA[132], cfB[132];   // MODE1 coefs, stride-33 (conflict-free)
    __shared__ float pr_pool[12], pr_y1[12], pr_pin[12], pr_sst[8][2];
    const int hb = blockIdx.x, b = blockIdx.y;
    const int hp = ((hb & 7) << 2) | (hb >> 3);   // XCD band swizzle (bijective 0..31)
    const int h0 = hp * 2;
    const int tid = threadIdx.x, lane = tid & 63, wid = tid >> 6;
    const int wm = wid & 1, wn = wid >> 1;
    const int l31 = lane & 31;
    const int rr = tid >> 8, pp = (tid >> 2) & 63, ck = tid & 3;
    const int swz = (pp & 15) << 4;

    float fv[32]; short8 sv[4];
    float fv2[32]; short8 sv2[4];

#define LOADCHUNK(r, fvv, svv, val) do { \
    const int hi_ = h0 + (r) - 1; \
    val = (hi_ >= 0 && hi_ < 64); \
    if (val) { \
        const size_t px_ = (size_t)((b * 64 + hi_) * 64 + pp); \
        if (MODE == 0) { \
            const float* sp_ = (const float*)inp + px_ * 128 + 12 + ck * 32; \
            if (ck < 3) { \
                _Pragma("unroll") for (int j = 0; j < 8; ++j) *(float4*)&fvv[j * 4] = ((const float4*)sp_)[j]; \
            } else { \
                _Pragma("unroll") for (int j = 0; j < 5; ++j) *(float4*)&fvv[j * 4] = ((const float4*)sp_)[j]; \
                _Pragma("unroll") for (int e = 20; e < 32; ++e) fvv[e] = 0.f; \
            } \
        } else { \
            const u16* sp_ = (const u16*)inp + px_ * 128 + ck * 32; \
            _Pragma("unroll") for (int k = 0; k < 4; ++k) svv[k] = ((const short8*)sp_)[k]; \
        } \
    } \
} while (0)

#define WRITECHUNK(r, fvv, svv, val) do { \
    u16 t_[32]; \
    if (val) { \
        if (MODE == 0) { \
            _Pragma("unroll") for (int e = 0; e < 32; ++e) t_[e] = f2bf(fvv[e]); \
        } else { \
            _Pragma("unroll") for (int e = 0; e < 32; ++e) { \
                int c_ = ck * 32 + e; \
                float f_ = bf2f((u16)svv[e >> 3][e & 7]); \
                float w_ = swishf(f_ * cfA[ck * 33 + e] + cfB[ck * 33 + e]); \
                t_[e] = (c_ < CC) ? f2bf(w_) : (u16)0; \
            } \
        } \
    } else { \
        _Pragma("unroll") for (int e = 0; e < 32; ++e) t_[e] = 0; \
    } \
    char* rb_ = (char*)As + ((r) * 64 + pp) * 256; \
    _Pragma("unroll") for (int k = 0; k < 4; ++k) \
        *(short8*)(rb_ + ((ck * 64 + k * 16) ^ swz)) = *(const short8*)&t_[k * 8]; \
} while (0)

    bool valA, valC;
    if (MODE == 1) {
        // issue all staging loads first; prologue compute hides under their latency
        LOADCHUNK(rr, fv, sv, valA);
        LOADCHUNK(2 + rr, fv2, sv2, valC);

        // ---- fused k_mid0: pooled -> circuit1 -> GN0 stats -> FiLM coefs ----
        if (tid < 12) {
            float s = 0.f;
#pragma unroll
            for (int k = 0; k < 8; ++k) s += part[(b * 8 + k) * 12 + tid];
            pr_pool[tid] = s * (1.f / 4096.f);
        }
        __syncthreads();
        if (tid < 3) {
            float z[4];
            run_circuit(&pr_pool[tid * 4], qp + tid * 4, z);
#pragma unroll
            for (int w = 0; w < 4; ++w) pr_y1[tid * 4 + w] = z[w];
        }
        __syncthreads();
        if (tid < 8) {
            const int g = tid;
            float S = 0.f, SS = 0.f;
#pragma unroll
            for (int e = 0; e < 16; ++e) {
                int orig = g * 16 + e;
                if (orig >= 12) {
                    int cc = orig - 12;
                    S += csin[(b * 128 + cc) * 2];
                    SS += csin[(b * 128 + cc) * 2 + 1];
                }
            }
            if (g == 0) {
#pragma unroll
                for (int c = 0; c < 12; ++c) {
                    float v = pr_y1[c];
                    S += 4096.f * v;
                    SS += 4096.f * v * v;
                }
            }
            float mu = S * (1.f / 65536.f);
            float var = SS * (1.f / 65536.f) - mu * mu;
            pr_sst[g][0] = mu;
            pr_sst[g][1] = rsqrtf(var + 1e-6f);
        }
        __syncthreads();
        if (tid < 128) {
            const int chn = tid, g = chn >> 4;
            float mu = pr_sst[g][0], isd = pr_sst[g][1];
            float a = isd * gs[chn];
            float bb = gb[chn] - mu * a;
            float sc = t[b * 256 + chn], sh = t[b * 256 + 128 + chn];
            float Af = a * (1.f + sc);
            float Bf = bb * (1.f + sc) + sh;
            if (chn >= 12) {
                int cc = chn - 12;
                cfA[(cc >> 5) * 33 + (cc & 31)] = Af;
                cfB[(cc >> 5) * 33 + (cc & 31)] = Bf;
            } else {
                pr_pin[chn] = swishf(pr_y1[chn] * Af + Bf);
            }
        }
        __syncthreads();                  // cf + pin visible
        if (hb == 0 && tid < 3) {         // one block per batch emits y2
            float z[4];
            run_circuit(&pr_pin[tid * 4], qp + tid * 4, z);
#pragma unroll
            for (int w = 0; w < 4; ++w) y2out[b * 12 + tid * 4 + w] = z[w];
        }
        WRITECHUNK(rr, fv, sv, valA);
    } else {
        LOADCHUNK(rr, fv, sv, valA);
        WRITECHUNK(rr, fv, sv, valA);
        LOADCHUNK(2 + rr, fv2, sv2, valC);   // lands under the p=0 phase
    }

    // B prologue: ring depth 4, one 32-oc fragment per wave per step
    const u16* bp = kqp + (size_t)wn * 512 + (size_t)lane * 8;
    short8 breg[4];
#pragma unroll
    for (int s = 0; s < 4; ++s) breg[s] = *(const short8*)(bp + ((size_t)s << 11));

    // A-frag addressing (static arrays, compile-time indexed)
    const int kh16 = (lane >> 5) << 4;
    int coloff[2][3], colswz[2][3];
#pragma unroll
    for (int mf = 0; mf < 2; ++mf)
#pragma unroll
        for (int q = 0; q < 3; ++q) {
            int c = mf * 32 + l31 + q - 1;
            int cc = c < 0 ? 0 : (c > 63 ? 63 : c);
            coloff[mf][q] = cc << 7;
            colswz[mf][q] = (cc & 15) << 4;
        }
    const bool e0 = (l31 == 0), e1 = (l31 == 31);
    const short8 zero8 = {0, 0, 0, 0, 0, 0, 0, 0};
    const int rowb = wm * 8192;

    asm volatile("s_waitcnt lgkmcnt(0)" ::: "memory");
    __builtin_amdgcn_s_barrier();         // raw: phase-C vmcnt stays outstanding

    f32x16 acc[2];
#pragma unroll
    for (int mf = 0; mf < 2; ++mf)
#pragma unroll
        for (int r = 0; r < 16; ++r) acc[mf][r] = 0.f;

#define AREAD(dst, s) do { \
    const int tap_ = (s) >> 3, p_ = tap_ / 3, q_ = tap_ % 3; \
    const int chb_ = ((s) & 7) << 5; \
    dst[0] = *(const short8*)&As[rowb + p_ * 8192 + coloff[0][q_] + (((chb_ + kh16) ^ colswz[0][q_]) >> 1)]; \
    dst[1] = *(const short8*)&As[rowb + p_ * 8192 + coloff[1][q_] + (((chb_ + kh16) ^ colswz[1][q_]) >> 1)]; \
} while (0)

#define STEP(s, base, lim) do { \
    const int cur_ = ((s) - (base)) & 1, nxt_ = cur_ ^ 1; \
    if ((s) + 1 < (lim)) AREAD(afr[nxt_], (s) + 1); \
    const int q_ = ((s) >> 3) % 3; \
    short8 a0_ = afr[cur_][0], a1_ = afr[cur_][1]; \
    if (q_ == 0) a0_ = e0 ? zero8 : a0_; \
    if (q_ == 2) a1_ = e1 ? zero8 : a1_; \
    __builtin_amdgcn_s_setprio(1); \
    acc[0] = __builtin_amdgcn_mfma_f32_32x32x16_bf16(a0_, breg[(s) & 3], acc[0], 0, 0, 0); \
    acc[1] = __builtin_amdgcn_mfma_f32_32x32x16_bf16(a1_, breg[(s) & 3], acc[1], 0, 0, 0); \
    __builtin_amdgcn_s_setprio(0); \
    if ((s) + 4 < 72) breg[(s) & 3] = *(const short8*)(bp + ((size_t)((s) + 4) << 11)); \
} while (0)

    short8 afr[2][2];
    AREAD(afr[0], 0);
#pragma unroll
    for (int s = 0; s < 24; ++s) STEP(s, 0, 24);     // p=0 taps (LDS rows wm..wm+1)

    WRITECHUNK(2 + rr, fv2, sv2, valC);              // loads arrived during p=0
    asm volatile("s_waitcnt lgkmcnt(0)" ::: "memory");
    __builtin_amdgcn_s_barrier();

    AREAD(afr[0], 24);
#pragma unroll
    for (int s = 24; s < 72; ++s) STEP(s, 24, 72);   // p=1,2 taps

    // ---- epilogue: bias, csum, LDS repack -> coalesced bf16 stores ----
    const int oc = wn * 32 + l31;
    const float bv = (oc < CC) ? bias[oc] : 0.f;
    float cs = 0.f, cq = 0.f;
    const int rbase = (lane >> 5) << 2;

    asm volatile("s_waitcnt lgkmcnt(0)" ::: "memory");
    __builtin_amdgcn_s_barrier();                    // all AREADs done; reuse As
#pragma unroll
    for (int mf = 0; mf < 2; ++mf) {
#pragma unroll
        for (int r = 0; r < 16; ++r) {
            int drow = (r & 3) + ((r >> 2) << 3) + rbase;
            int flat = wm * 64 + mf * 32 + drow;     // 0..127 within tile
            float v = acc[mf][r] + bv;
            As[flat * 128 + oc] = f2bf(v);
            cs += v;
            cq += v * v;
        }
    }
    asm volatile("s_waitcnt lgkmcnt(0)" ::: "memory");
    __builtin_amdgcn_s_barrier();
    {
        size_t obase = (size_t)(b * 4096 + h0 * 64) * 128;
#pragma unroll
        for (int k = 0; k < 4; ++k)
            *(short8*)&outp[obase + k * 4096 + tid * 8] = *(const short8*)&As[k * 4096 + tid * 8];
    }
    cs += __shfl_xor(cs, 32);
    cq += __shfl_xor(cq, 32);
    if (lane < 32) {
        atomicAdd(&csum[(b * 128 + oc) * 2], cs);
        atomicAdd(&csum[(b * 128 + oc) * 2 + 1], cq);
    }
#undef LOADCHUNK
#undef WRITECHUNK
#undef AREAD
#undef STEP
}

// ---------------- fused: GN1 stats + coefs + quantum output ----------------
__global__ void k_mid1(const float* __restrict__ csum, const float* __restrict__ y2,
                       const float* __restrict__ gs, const float* __restrict__ gb,
                       float* __restrict__ A2, float* __restrict__ B2,
                       float* __restrict__ oq) {
    __shared__ float sst[128][2];
    int tid = threadIdx.x;
    if (tid < 128) {
        int b = tid >> 3, g = tid & 7;
        float S = 0.f, SS = 0.f;
#pragma unroll
        for (int e = 0; e < 16; ++e) {
            int orig = g * 16 + e;
            if (orig >= 12) {
                int cc = orig - 12;
                S += csum[(b * 128 + cc) * 2];
                SS += csum[(b * 128 + cc) * 2 + 1];
            }
        }
        if (g == 0) {
#pragma unroll
            for (int c = 0; c < 12; ++c) {
                float v = y2[b * 12 + c];
                S += 4096.f * v;
                SS += 4096.f * v * v;
            }
        }
        float mu = S * (1.f / 65536.f);
        float var = SS * (1.f / 65536.f) - mu * mu;
        sst[tid][0] = mu;
        sst[tid][1] = rsqrtf(var + 1e-6f);
    }
    __syncthreads();
    for (int i = tid; i < 2048; i += 256) {
        int b = i >> 7, c = i & 127, g = c >> 4;
        float mu = sst[b * 8 + g][0], isd = sst[b * 8 + g][1];
        float a = isd * gs[c];
        A2[i] = a;
        B2[i] = gb[c] - mu * a;
    }
    if (tid < 192) {
        int b = tid / 12, c = tid % 12;
        float mu = sst[b * 8][0], isd = sst[b * 8][1];
        float a = isd * gs[c];
        float bb = gb[c] - mu * a;
        oq[b * 12 + c] = swishf(y2[b * 12 + c] * a + bb);
    }
}

// ---------------- out = x + swish(A2*v + B2) ----------------
__global__ void k_final(const float* __restrict__ x, const u16* __restrict__ co,
                        const float* __restrict__ A2, const float* __restrict__ B2,
                        const float* __restrict__ oq, float* __restrict__ outp) {
    const int t = blockIdx.x, b = blockIdx.y;
    const int seg = t >> 6, hraw = t & 63;
    const int h = ((hraw & 7) << 3) | (hraw >> 3);
    const int tid = threadIdx.x;
    const size_t px = (size_t)(b * 64 + h) * 64 + seg * 8 + (tid >> 5);
    const int c4 = tid & 31, c = c4 * 4;
    float4 xv = *(const float4*)(x + px * CDIM + c);
    float4 r;
    if (c4 < 3) {
        const float* q = oq + b * 12 + c;
        r.x = xv.x + q[0]; r.y = xv.y + q[1]; r.z = xv.z + q[2]; r.w = xv.w + q[3];
    } else {
        int cc = c - 12;
        const u16* hp = co + px * 128 + cc;
        float4 a = *(const float4*)(A2 + b * 128 + c);
        float4 bb = *(const float4*)(B2 + b * 128 + c);
        r.x = xv.x + swishf(bf2f(hp[0]) * a.x + bb.x);
        r.y = xv.y + swishf(bf2f(hp[1]) * a.y + bb.y);
        r.z = xv.z + swishf(bf2f(hp[2]) * a.z + bb.z);
        r.w = xv.w + swishf(bf2f(hp[3]) * a.w + bb.w);
    }
    *(float4*)(outp + px * CDIM + c) = r;
}

extern "C" void kernel_launch(void* const* d_in, const int* in_sizes, int n_in,
                              void* d_out, int out_size, void* d_ws, size_t ws_size,
                              hipStream_t stream) {
    const float* x        = (const float*)d_in[0];
    const float* time_emb = (const float*)d_in[1];
    const float* qparams  = (const float*)d_in[2];
    const float* c0k      = (const float*)d_in[3];
    const float* c0b      = (const float*)d_in[4];
    const float* c1k      = (const float*)d_in[5];
    const float* c1b      = (const float*)d_in[6];
    const float* g0s      = (const float*)d_in[7];
    const float* g0b      = (const float*)d_in[8];
    const float* g1s      = (const float*)d_in[9];
    const float* g1b      = (const float*)d_in[10];
    const float* tw       = (const float*)d_in[11];
    const float* tb       = (const float*)d_in[12];
    float* outp = (float*)d_out;
    float* ws = (float*)d_ws;

    size_t o = 0;
    auto alloc = [&](size_t n) { size_t r = o; o += (n + 15) & ~(size_t)15; return r; };
    float* part   = ws + alloc(1536);
    float* csums  = ws + alloc(8192);            // csum0 | csum1
    float* csum0  = csums;
    float* csum1  = csums + 4096;
    float* t      = ws + alloc(4096);
    float* A2     = ws + alloc(2048);
    float* B2     = ws + alloc(2048);
    float* y2     = ws + alloc(192);
    float* oq     = ws + alloc(192);
    u16* kqp0     = (u16*)(ws + alloc(73728));   // 72*4*512 bf16
    u16* kqp1     = (u16*)(ws + alloc(73728));
    u16* convA    = (u16*)(ws + alloc(4194304)); // [16][4096][128] bf16 (conv0 out)
    u16* convB    = (u16*)(ws + alloc(4194304)); // conv1 out

    k_misc<<<416, 256, 0, stream>>>(x, part, csums, time_emb, tw, tb, t,
                                    c0k, c1k, kqp0, kqp1);

    dim3 cgrid(32, 16);
    k_conv<0><<<cgrid, 512, 0, stream>>>(x, kqp0, c0b, convA, csum0,
                                         nullptr, nullptr, nullptr, nullptr,
                                         nullptr, nullptr, nullptr);
    k_conv<1><<<cgrid, 512, 0, stream>>>(convA, kqp1, c1b, convB, csum1,
                                         part, csum0, t, g0s, g0b, qparams, y2);
    k_mid1<<<1, 256, 0, stream>>>(csum1, y2, g1s, g1b, A2, B2, oq);
    k_final<<<dim3(512, 16), 256, 0, stream>>>(x, convB, A2, B2, oq, outp);
}

// Round 21
// 109.274 us; speedup vs baseline: 1.0618x; 1.0277x over previous
//
#include <hip/hip_runtime.h>
#include <math.h>

#define BATCH 16
#define NPX 4096            // 64*64
#define CDIM 128
#define CC 116              // conv channels
#define KTAPS 1044          // 9*116

using u16 = unsigned short;
typedef __attribute__((ext_vector_type(8))) short short8;
typedef __attribute__((ext_vector_type(16))) float f32x16;

__device__ __forceinline__ float swishf(float z) {
    return z / (1.f + __expf(-z));
}
__device__ __forceinline__ float bf2f(u16 u) {
    union { unsigned int i; float f; } v; v.i = ((unsigned int)u) << 16; return v.f;
}
__device__ __forceinline__ u16 f2bf(float f) {
    union { float f; unsigned int i; } v; v.f = f;
    unsigned int r = v.i + 0x7fffu + ((v.i >> 16) & 1u);
    return (u16)(r >> 16);
}

// ---------------- 4-qubit circuit ----------------
__device__ void run_circuit(const float* ang, const float* th, float* z) {
    float ar[16], ai[16];
#pragma unroll
    for (int k = 0; k < 16; ++k) { ar[k] = 0.f; ai[k] = 0.f; }
    ar[0] = 1.f;
#pragma unroll
    for (int pass = 0; pass < 2; ++pass) {
        const float* a = pass ? th : ang;
#pragma unroll
        for (int w = 0; w < 4; ++w) {
            float half = 0.5f * a[w];
            float cth = cosf(half), sth = sinf(half);
            int m = 1 << (3 - w);
#pragma unroll
            for (int k = 0; k < 16; ++k) {
                if (k & m) continue;
                int k2 = k | m;
                float r0 = ar[k], i0 = ai[k], r1 = ar[k2], i1 = ai[k2];
                ar[k]  = cth * r0 + sth * i1;
                ai[k]  = cth * i0 - sth * r1;
                ar[k2] = sth * i0 + cth * r1;
                ai[k2] = -sth * r0 + cth * i1;
            }
        }
    }
#pragma unroll
    for (int e = 0; e < 4; ++e) {
        const int cwi[4] = {0, 1, 2, 3};
        const int twi[4] = {1, 2, 3, 0};
        int mc = 1 << (3 - cwi[e]), mt = 1 << (3 - twi[e]);
#pragma unroll
        for (int k = 0; k < 16; ++k) {
            if ((k & mc) && !(k & mt)) {
                int k2 = k | mt;
                float tr = ar[k]; ar[k] = ar[k2]; ar[k2] = tr;
                float ti = ai[k]; ai[k] = ai[k2]; ai[k2] = ti;
            }
        }
    }
    float zz[4] = {0.f, 0.f, 0.f, 0.f};
#pragma unroll
    for (int k = 0; k < 16; ++k) {
        float p = ar[k] * ar[k] + ai[k] * ai[k];
#pragma unroll
        for (int w = 0; w < 4; ++w) zz[w] += ((k >> (3 - w)) & 1) ? -p : p;
    }
#pragma unroll
    for (int w = 0; w < 4; ++w) z[w] = zz[w];
}

// -------- merged: pooled partials (bx<128) | csum zero (128..143) | time MLP
//          (144..159) | weight-standardize+pack (160..415) --------
__global__ void k_misc(const float* __restrict__ x, float* __restrict__ part,
                       float* __restrict__ csums,
                       const float* __restrict__ te, const float* __restrict__ W,
                       const float* __restrict__ tb, float* __restrict__ t,
                       const float* __restrict__ K0, const float* __restrict__ K1,
                       u16* __restrict__ kqp0, u16* __restrict__ kqp1) {
    const int bx = blockIdx.x, tid = threadIdx.x;
    __shared__ float red[12][256];
    __shared__ float se[512];
    __shared__ float rs[256], rss[256], mb[2];
    if (bx < 128) {
        const int b = bx >> 3, seg = bx & 7;
        float s[12];
#pragma unroll
        for (int c = 0; c < 12; ++c) s[c] = 0.f;
        const float* xb = x + (size_t)(b * 4096 + seg * 512) * CDIM;
#pragma unroll
        for (int i = 0; i < 2; ++i) {
            const float4* p = (const float4*)(xb + (size_t)(tid + i * 256) * CDIM);
            float4 v0 = p[0], v1 = p[1], v2 = p[2];
            s[0] += v0.x; s[1] += v0.y; s[2] += v0.z; s[3] += v0.w;
            s[4] += v1.x; s[5] += v1.y; s[6] += v1.z; s[7] += v1.w;
            s[8] += v2.x; s[9] += v2.y; s[10] += v2.z; s[11] += v2.w;
        }
#pragma unroll
        for (int c = 0; c < 12; ++c) red[c][tid] = s[c];
        __syncthreads();
        for (int st = 128; st > 0; st >>= 1) {
            if (tid < st) {
#pragma unroll
                for (int c = 0; c < 12; ++c) red[c][tid] += red[c][tid + st];
            }
            __syncthreads();
        }
        if (tid < 12) part[bx * 12 + tid] = red[tid][0];
        return;
    }
    if (bx < 144) {
        int i = (bx - 128) * 256 + tid;
        csums[i * 2] = 0.f;
        csums[i * 2 + 1] = 0.f;
        return;
    }
    if (bx < 160) {
        const int b = bx - 144;
        for (int k = tid; k < 512; k += 256) se[k] = swishf(te[b * 512 + k]);
        __syncthreads();
        float acc = tb[tid];
        for (int k = 0; k < 512; ++k) acc += se[k] * W[k * 256 + tid];
        t[b * 256 + tid] = acc;
        return;
    }
    const int r = bx - 160;
    const float* K = (r >> 7) ? K1 : K0;
    u16* kqp = (r >> 7) ? kqp1 : kqp0;
    const int o = r & 127;
    float s = 0.f, ss = 0.f;
    if (o < CC) {
        for (int idx = tid; idx < KTAPS; idx += 256) {
            float v = K[(size_t)idx * CC + o];
            s += v; ss += v * v;
        }
    }
    rs[tid] = s; rss[tid] = ss;
    __syncthreads();
    for (int st = 128; st > 0; st >>= 1) {
        if (tid < st) { rs[tid] += rs[tid + st]; rss[tid] += rss[tid + st]; }
        __syncthreads();
    }
    if (tid == 0) {
        float m = rs[0] * (1.f / KTAPS);
        float var = rss[0] * (1.f / KTAPS) - m * m;
        mb[0] = m;
        mb[1] = rsqrtf(var + 1e-5f);
    }
    __syncthreads();
    float m = mb[0], inv = mb[1];
    for (int idx = tid; idx < 1152; idx += 256) {
        int tap = idx >> 7, ic = idx & 127;
        float v = 0.f;
        if (o < CC && ic < CC) v = (K[((size_t)tap * CC + ic) * CC + o] - m) * inv;
        int step = tap * 8 + (ic >> 4);
        int lane2 = ((ic >> 3) & 1) * 32 + (o & 31);
        int j = ic & 7;
        kqp[(size_t)(step * 4 + (o >> 5)) * 512 + lane2 * 8 + j] = f2bf(v);
    }
}

// ---------------- MFMA 32x32x16 implicit-GEMM conv, 128px x 128oc, 512 threads ----
// R17 skeleton. MODE 0: hb==0 blocks compute circuit-1 (y1) in the epilogue
// (16/512 blocks, overlapped). MODE 1: lightweight prologue reads y1 + csum0,
// builds FiLM coefs (no circuit); hb==0 blocks emit y2. k_mid0 eliminated.
template <int MODE>
__launch_bounds__(512, 2)
__global__ void k_conv(const void* __restrict__ inp, const u16* __restrict__ kqp,
                       const float* __restrict__ bias, u16* __restrict__ outp,
                       float* __restrict__ csum,
                       const float* __restrict__ part, const float* __restrict__ csin,
                       const float* __restrict__ t, const float* __restrict__ gs,
                       const float* __restrict__ gb, const float* __restrict__ qp,
                       const float* __restrict__ y1in, float* __restrict__ yout) {
    __shared__ u16 As[32768];      // 64KB: 4 rows x 64 px x 128 ch (then repack)
    __shared__ float cfA[132], cfB[132];   // MODE1 coefs, stride-33 (conflict-free)
    __shared__ float pr_y1[12], pr_pin[12], pr_sst[8][2];
    const int hb = blockIdx.x, b = blockIdx.y;
    const int hp = ((hb & 7) << 2) | (hb >> 3);   // XCD band swizzle (bijective 0..31)
    const int h0 = hp * 2;
    const int tid = threadIdx.x, lane = tid & 63, wid = tid >> 6;
    const int wm = wid & 1, wn = wid >> 1;
    const int l31 = lane & 31;
    const int rr = tid >> 8, pp = (tid >> 2) & 63, ck = tid & 3;
    const int swz = (pp & 15) << 4;

    float fv[32]; short8 sv[4];
    float fv2[32]; short8 sv2[4];

#define LOADCHUNK(r, fvv, svv, val) do { \
    const int hi_ = h0 + (r) - 1; \
    val = (hi_ >= 0 && hi_ < 64); \
    if (val) { \
        const size_t px_ = (size_t)((b * 64 + hi_) * 64 + pp); \
        if (MODE == 0) { \
            const float* sp_ = (const float*)inp + px_ * 128 + 12 + ck * 32; \
            if (ck < 3) { \
                _Pragma("unroll") for (int j = 0; j < 8; ++j) *(float4*)&fvv[j * 4] = ((const float4*)sp_)[j]; \
            } else { \
                _Pragma("unroll") for (int j = 0; j < 5; ++j) *(float4*)&fvv[j * 4] = ((const float4*)sp_)[j]; \
                _Pragma("unroll") for (int e = 20; e < 32; ++e) fvv[e] = 0.f; \
            } \
        } else { \
            const u16* sp_ = (const u16*)inp + px_ * 128 + ck * 32; \
            _Pragma("unroll") for (int k = 0; k < 4; ++k) svv[k] = ((const short8*)sp_)[k]; \
        } \
    } \
} while (0)

#define WRITECHUNK(r, fvv, svv, val) do { \
    u16 t_[32]; \
    if (val) { \
        if (MODE == 0) { \
            _Pragma("unroll") for (int e = 0; e < 32; ++e) t_[e] = f2bf(fvv[e]); \
        } else { \
            _Pragma("unroll") for (int e = 0; e < 32; ++e) { \
                int c_ = ck * 32 + e; \
                float f_ = bf2f((u16)svv[e >> 3][e & 7]); \
                float w_ = swishf(f_ * cfA[ck * 33 + e] + cfB[ck * 33 + e]); \
                t_[e] = (c_ < CC) ? f2bf(w_) : (u16)0; \
            } \
        } \
    } else { \
        _Pragma("unroll") for (int e = 0; e < 32; ++e) t_[e] = 0; \
    } \
    char* rb_ = (char*)As + ((r) * 64 + pp) * 256; \
    _Pragma("unroll") for (int k = 0; k < 4; ++k) \
        *(short8*)(rb_ + ((ck * 64 + k * 16) ^ swz)) = *(const short8*)&t_[k * 8]; \
} while (0)

    bool valA, valC;
    if (MODE == 1) {
        // issue all staging loads first; prologue math hides under their latency
        LOADCHUNK(rr, fv, sv, valA);
        LOADCHUNK(2 + rr, fv2, sv2, valC);

        // ---- lightweight FiLM-coef prologue (y1 precomputed by conv0) ----
        if (tid < 12) pr_y1[tid] = y1in[b * 12 + tid];
        __syncthreads();
        if (tid < 8) {
            const int g = tid;
            float S = 0.f, SS = 0.f;
#pragma unroll
            for (int e = 0; e < 16; ++e) {
                int orig = g * 16 + e;
                if (orig >= 12) {
                    int cc = orig - 12;
                    S += csin[(b * 128 + cc) * 2];
                    SS += csin[(b * 128 + cc) * 2 + 1];
                }
            }
            if (g == 0) {
#pragma unroll
                for (int c = 0; c < 12; ++c) {
                    float v = pr_y1[c];
                    S += 4096.f * v;
                    SS += 4096.f * v * v;
                }
            }
            float mu = S * (1.f / 65536.f);
            float var = SS * (1.f / 65536.f) - mu * mu;
            pr_sst[g][0] = mu;
            pr_sst[g][1] = rsqrtf(var + 1e-6f);
        }
        __syncthreads();
        if (tid < 128) {
            const int chn = tid, g = chn >> 4;
            float mu = pr_sst[g][0], isd = pr_sst[g][1];
            float a = isd * gs[chn];
            float bb = gb[chn] - mu * a;
            float sc = t[b * 256 + chn], sh = t[b * 256 + 128 + chn];
            float Af = a * (1.f + sc);
            float Bf = bb * (1.f + sc) + sh;
            if (chn >= 12) {
                int cc = chn - 12;
                cfA[(cc >> 5) * 33 + (cc & 31)] = Af;
                cfB[(cc >> 5) * 33 + (cc & 31)] = Bf;
            } else {
                pr_pin[chn] = swishf(pr_y1[chn] * Af + Bf);
            }
        }
        __syncthreads();                  // cf + pin visible
        if (hb == 0 && tid < 3) {         // one block per batch emits y2
            float z[4];
            run_circuit(&pr_pin[tid * 4], qp + tid * 4, z);
#pragma unroll
            for (int w = 0; w < 4; ++w) yout[b * 12 + tid * 4 + w] = z[w];
        }
        WRITECHUNK(rr, fv, sv, valA);
    } else {
        LOADCHUNK(rr, fv, sv, valA);
        WRITECHUNK(rr, fv, sv, valA);
        LOADCHUNK(2 + rr, fv2, sv2, valC);   // lands under the p=0 phase
    }

    // B prologue: ring depth 4, one 32-oc fragment per wave per step
    const u16* bp = kqp + (size_t)wn * 512 + (size_t)lane * 8;
    short8 breg[4];
#pragma unroll
    for (int s = 0; s < 4; ++s) breg[s] = *(const short8*)(bp + ((size_t)s << 11));

    // A-frag addressing (static arrays, compile-time indexed)
    const int kh16 = (lane >> 5) << 4;
    int coloff[2][3], colswz[2][3];
#pragma unroll
    for (int mf = 0; mf < 2; ++mf)
#pragma unroll
        for (int q = 0; q < 3; ++q) {
            int c = mf * 32 + l31 + q - 1;
            int cc = c < 0 ? 0 : (c > 63 ? 63 : c);
            coloff[mf][q] = cc << 7;
            colswz[mf][q] = (cc & 15) << 4;
        }
    const bool e0 = (l31 == 0), e1 = (l31 == 31);
    const short8 zero8 = {0, 0, 0, 0, 0, 0, 0, 0};
    const int rowb = wm * 8192;

    asm volatile("s_waitcnt lgkmcnt(0)" ::: "memory");
    __builtin_amdgcn_s_barrier();         // raw: phase-C vmcnt stays outstanding

    f32x16 acc[2];
#pragma unroll
    for (int mf = 0; mf < 2; ++mf)
#pragma unroll
        for (int r = 0; r < 16; ++r) acc[mf][r] = 0.f;

#define AREAD(dst, s) do { \
    const int tap_ = (s) >> 3, p_ = tap_ / 3, q_ = tap_ % 3; \
    const int chb_ = ((s) & 7) << 5; \
    dst[0] = *(const short8*)&As[rowb + p_ * 8192 + coloff[0][q_] + (((chb_ + kh16) ^ colswz[0][q_]) >> 1)]; \
    dst[1] = *(const short8*)&As[rowb + p_ * 8192 + coloff[1][q_] + (((chb_ + kh16) ^ colswz[1][q_]) >> 1)]; \
} while (0)

#define STEP(s, base, lim) do { \
    const int cur_ = ((s) - (base)) & 1, nxt_ = cur_ ^ 1; \
    if ((s) + 1 < (lim)) AREAD(afr[nxt_], (s) + 1); \
    const int q_ = ((s) >> 3) % 3; \
    short8 a0_ = afr[cur_][0], a1_ = afr[cur_][1]; \
    if (q_ == 0) a0_ = e0 ? zero8 : a0_; \
    if (q_ == 2) a1_ = e1 ? zero8 : a1_; \
    __builtin_amdgcn_s_setprio(1); \
    acc[0] = __builtin_amdgcn_mfma_f32_32x32x16_bf16(a0_, breg[(s) & 3], acc[0], 0, 0, 0); \
    acc[1] = __builtin_amdgcn_mfma_f32_32x32x16_bf16(a1_, breg[(s) & 3], acc[1], 0, 0, 0); \
    __builtin_amdgcn_s_setprio(0); \
    if ((s) + 4 < 72) breg[(s) & 3] = *(const short8*)(bp + ((size_t)((s) + 4) << 11)); \
} while (0)

    short8 afr[2][2];
    AREAD(afr[0], 0);
#pragma unroll
    for (int s = 0; s < 24; ++s) STEP(s, 0, 24);     // p=0 taps (LDS rows wm..wm+1)

    WRITECHUNK(2 + rr, fv2, sv2, valC);              // loads arrived during p=0
    asm volatile("s_waitcnt lgkmcnt(0)" ::: "memory");
    __builtin_amdgcn_s_barrier();

    AREAD(afr[0], 24);
#pragma unroll
    for (int s = 24; s < 72; ++s) STEP(s, 24, 72);   // p=1,2 taps

    // ---- epilogue: bias, csum, LDS repack -> coalesced bf16 stores ----
    const int oc = wn * 32 + l31;
    const float bv = (oc < CC) ? bias[oc] : 0.f;
    float cs = 0.f, cq = 0.f;
    const int rbase = (lane >> 5) << 2;

    asm volatile("s_waitcnt lgkmcnt(0)" ::: "memory");
    __builtin_amdgcn_s_barrier();                    // all AREADs done; reuse As
#pragma unroll
    for (int mf = 0; mf < 2; ++mf) {
#pragma unroll
        for (int r = 0; r < 16; ++r) {
            int drow = (r & 3) + ((r >> 2) << 3) + rbase;
            int flat = wm * 64 + mf * 32 + drow;     // 0..127 within tile
            float v = acc[mf][r] + bv;
            As[flat * 128 + oc] = f2bf(v);
            cs += v;
            cq += v * v;
        }
    }
    asm volatile("s_waitcnt lgkmcnt(0)" ::: "memory");
    __builtin_amdgcn_s_barrier();
    {
        size_t obase = (size_t)(b * 4096 + h0 * 64) * 128;
#pragma unroll
        for (int k = 0; k < 4; ++k)
            *(short8*)&outp[obase + k * 4096 + tid * 8] = *(const short8*)&As[k * 4096 + tid * 8];
    }
    cs += __shfl_xor(cs, 32);
    cq += __shfl_xor(cq, 32);
    if (lane < 32) {
        atomicAdd(&csum[(b * 128 + oc) * 2], cs);
        atomicAdd(&csum[(b * 128 + oc) * 2 + 1], cq);
    }

    // ---- MODE 0, hb==0: compute circuit-1 (y1) -- 16/512 blocks, overlapped ----
    if (MODE == 0 && hb == 0) {
        __syncthreads();
        if (tid < 12) {
            float s = 0.f;
#pragma unroll
            for (int k = 0; k < 8; ++k) s += part[(b * 8 + k) * 12 + tid];
            pr_y1[tid] = s * (1.f / 4096.f);
        }
        __syncthreads();
        if (tid < 3) {
            float z[4];
            run_circuit(&pr_y1[tid * 4], qp + tid * 4, z);
#pragma unroll
            for (int w = 0; w < 4; ++w) yout[b * 12 + tid * 4 + w] = z[w];
        }
    }
#undef LOADCHUNK
#undef WRITECHUNK
#undef AREAD
#undef STEP
}

// ---------------- fused: GN1 stats + coefs + quantum output ----------------
__global__ void k_mid1(const float* __restrict__ csum, const float* __restrict__ y2,
                       const float* __restrict__ gs, const float* __restrict__ gb,
                       float* __restrict__ A2, float* __restrict__ B2,
                       float* __restrict__ oq) {
    __shared__ float sst[128][2];
    int tid = threadIdx.x;
    if (tid < 128) {
        int b = tid >> 3, g = tid & 7;
        float S = 0.f, SS = 0.f;
#pragma unroll
        for (int e = 0; e < 16; ++e) {
            int orig = g * 16 + e;
            if (orig >= 12) {
                int cc = orig - 12;
                S += csum[(b * 128 + cc) * 2];
                SS += csum[(b * 128 + cc) * 2 + 1];
            }
        }
        if (g == 0) {
#pragma unroll
            for (int c = 0; c < 12; ++c) {
                float v = y2[b * 12 + c];
                S += 4096.f * v;
                SS += 4096.f * v * v;
            }
        }
        float mu = S * (1.f / 65536.f);
        float var = SS * (1.f / 65536.f) - mu * mu;
        sst[tid][0] = mu;
        sst[tid][1] = rsqrtf(var + 1e-6f);
    }
    __syncthreads();
    for (int i = tid; i < 2048; i += 256) {
        int b = i >> 7, c = i & 127, g = c >> 4;
        float mu = sst[b * 8 + g][0], isd = sst[b * 8 + g][1];
        float a = isd * gs[c];
        A2[i] = a;
        B2[i] = gb[c] - mu * a;
    }
    if (tid < 192) {
        int b = tid / 12, c = tid % 12;
        float mu = sst[b * 8][0], isd = sst[b * 8][1];
        float a = isd * gs[c];
        float bb = gb[c] - mu * a;
        oq[b * 12 + c] = swishf(y2[b * 12 + c] * a + bb);
    }
}

// ---------------- out = x + swish(A2*v + B2) ----------------
__global__ void k_final(const float* __restrict__ x, const u16* __restrict__ co,
                        const float* __restrict__ A2, const float* __restrict__ B2,
                        const float* __restrict__ oq, float* __restrict__ outp) {
    const int t = blockIdx.x, b = blockIdx.y;
    const int seg = t >> 6, hraw = t & 63;
    const int h = ((hraw & 7) << 3) | (hraw >> 3);
    const int tid = threadIdx.x;
    const size_t px = (size_t)(b * 64 + h) * 64 + seg * 8 + (tid >> 5);
    const int c4 = tid & 31, c = c4 * 4;
    float4 xv = *(const float4*)(x + px * CDIM + c);
    float4 r;
    if (c4 < 3) {
        const float* q = oq + b * 12 + c;
        r.x = xv.x + q[0]; r.y = xv.y + q[1]; r.z = xv.z + q[2]; r.w = xv.w + q[3];
    } else {
        int cc = c - 12;
        const u16* hp = co + px * 128 + cc;
        float4 a = *(const float4*)(A2 + b * 128 + c);
        float4 bb = *(const float4*)(B2 + b * 128 + c);
        r.x = xv.x + swishf(bf2f(hp[0]) * a.x + bb.x);
        r.y = xv.y + swishf(bf2f(hp[1]) * a.y + bb.y);
        r.z = xv.z + swishf(bf2f(hp[2]) * a.z + bb.z);
        r.w = xv.w + swishf(bf2f(hp[3]) * a.w + bb.w);
    }
    *(float4*)(outp + px * CDIM + c) = r;
}

extern "C" void kernel_launch(void* const* d_in, const int* in_sizes, int n_in,
                              void* d_out, int out_size, void* d_ws, size_t ws_size,
                              hipStream_t stream) {
    const float* x        = (const float*)d_in[0];
    const float* time_emb = (const float*)d_in[1];
    const float* qparams  = (const float*)d_in[2];
    const float* c0k      = (const float*)d_in[3];
    const float* c0b      = (const float*)d_in[4];
    const float* c1k      = (const float*)d_in[5];
    const float* c1b      = (const float*)d_in[6];
    const float* g0s      = (const float*)d_in[7];
    const float* g0b      = (const float*)d_in[8];
    const float* g1s      = (const float*)d_in[9];
    const float* g1b      = (const float*)d_in[10];
    const float* tw       = (const float*)d_in[11];
    const float* tb       = (const float*)d_in[12];
    float* outp = (float*)d_out;
    float* ws = (float*)d_ws;

    size_t o = 0;
    auto alloc = [&](size_t n) { size_t r = o; o += (n + 15) & ~(size_t)15; return r; };
    float* part   = ws + alloc(1536);
    float* csums  = ws + alloc(8192);            // csum0 | csum1
    float* csum0  = csums;
    float* csum1  = csums + 4096;
    float* t      = ws + alloc(4096);
    float* A2     = ws + alloc(2048);
    float* B2     = ws + alloc(2048);
    float* y1     = ws + alloc(192);
    float* y2     = ws + alloc(192);
    float* oq     = ws + alloc(192);
    u16* kqp0     = (u16*)(ws + alloc(73728));   // 72*4*512 bf16
    u16* kqp1     = (u16*)(ws + alloc(73728));
    u16* convA    = (u16*)(ws + alloc(4194304)); // [16][4096][128] bf16 (conv0 out)
    u16* convB    = (u16*)(ws + alloc(4194304)); // conv1 out

    k_misc<<<416, 256, 0, stream>>>(x, part, csums, time_emb, tw, tb, t,
                                    c0k, c1k, kqp0, kqp1);

    dim3 cgrid(32, 16);
    k_conv<0><<<cgrid, 512, 0, stream>>>(x, kqp0, c0b, convA, csum0,
                                         part, nullptr, nullptr, nullptr,
                                         nullptr, qparams, nullptr, y1);
    k_conv<1><<<cgrid, 512, 0, stream>>>(convA, kqp1, c1b, convB, csum1,
                                         nullptr, csum0, t, g0s, g0b, qparams, y1, y2);
    k_mid1<<<1, 256, 0, stream>>>(csum1, y2, g1s, g1b, A2, B2, oq);
    k_final<<<dim3(512, 16), 256, 0, stream>>>(x, convB, A2, B2, oq, outp);
}

// Round 22
// 109.110 us; speedup vs baseline: 1.0634x; 1.0015x over previous
//
#include <hip/hip_runtime.h>
#include <math.h>

#define BATCH 16
#define NPX 4096            // 64*64
#define CDIM 128
#define CC 116              // conv channels
#define KTAPS 1044          // 9*116

using u16 = unsigned short;
typedef __attribute__((ext_vector_type(8))) short short8;
typedef __attribute__((ext_vector_type(16))) float f32x16;

__device__ __forceinline__ float swishf(float z) {
    return z / (1.f + __expf(-z));
}
__device__ __forceinline__ float bf2f(u16 u) {
    union { unsigned int i; float f; } v; v.i = ((unsigned int)u) << 16; return v.f;
}
__device__ __forceinline__ u16 f2bf(float f) {
    union { float f; unsigned int i; } v; v.f = f;
    unsigned int r = v.i + 0x7fffu + ((v.i >> 16) & 1u);
    return (u16)(r >> 16);
}

// ---------------- 4-qubit circuit ----------------
__device__ void run_circuit(const float* ang, const float* th, float* z) {
    float ar[16], ai[16];
#pragma unroll
    for (int k = 0; k < 16; ++k) { ar[k] = 0.f; ai[k] = 0.f; }
    ar[0] = 1.f;
#pragma unroll
    for (int pass = 0; pass < 2; ++pass) {
        const float* a = pass ? th : ang;
#pragma unroll
        for (int w = 0; w < 4; ++w) {
            float half = 0.5f * a[w];
            float cth = cosf(half), sth = sinf(half);
            int m = 1 << (3 - w);
#pragma unroll
            for (int k = 0; k < 16; ++k) {
                if (k & m) continue;
                int k2 = k | m;
                float r0 = ar[k], i0 = ai[k], r1 = ar[k2], i1 = ai[k2];
                ar[k]  = cth * r0 + sth * i1;
                ai[k]  = cth * i0 - sth * r1;
                ar[k2] = sth * i0 + cth * r1;
                ai[k2] = -sth * r0 + cth * i1;
            }
        }
    }
#pragma unroll
    for (int e = 0; e < 4; ++e) {
        const int cwi[4] = {0, 1, 2, 3};
        const int twi[4] = {1, 2, 3, 0};
        int mc = 1 << (3 - cwi[e]), mt = 1 << (3 - twi[e]);
#pragma unroll
        for (int k = 0; k < 16; ++k) {
            if ((k & mc) && !(k & mt)) {
                int k2 = k | mt;
                float tr = ar[k]; ar[k] = ar[k2]; ar[k2] = tr;
                float ti = ai[k]; ai[k] = ai[k2]; ai[k2] = ti;
            }
        }
    }
    float zz[4] = {0.f, 0.f, 0.f, 0.f};
#pragma unroll
    for (int k = 0; k < 16; ++k) {
        float p = ar[k] * ar[k] + ai[k] * ai[k];
#pragma unroll
        for (int w = 0; w < 4; ++w) zz[w] += ((k >> (3 - w)) & 1) ? -p : p;
    }
#pragma unroll
    for (int w = 0; w < 4; ++w) z[w] = zz[w];
}

// -------- merged: pooled partials (bx<128) | csum zero (128..143) | time MLP
//          (144..159) | weight-standardize+pack (160..415) --------
__global__ void k_misc(const float* __restrict__ x, float* __restrict__ part,
                       float* __restrict__ csums,
                       const float* __restrict__ te, const float* __restrict__ W,
                       const float* __restrict__ tb, float* __restrict__ t,
                       const float* __restrict__ K0, const float* __restrict__ K1,
                       u16* __restrict__ kqp0, u16* __restrict__ kqp1) {
    const int bx = blockIdx.x, tid = threadIdx.x;
    __shared__ float red[12][256];
    __shared__ float se[512];
    __shared__ float rs[256], rss[256], mb[2];
    if (bx < 128) {
        const int b = bx >> 3, seg = bx & 7;
        float s[12];
#pragma unroll
        for (int c = 0; c < 12; ++c) s[c] = 0.f;
        const float* xb = x + (size_t)(b * 4096 + seg * 512) * CDIM;
#pragma unroll
        for (int i = 0; i < 2; ++i) {
            const float4* p = (const float4*)(xb + (size_t)(tid + i * 256) * CDIM);
            float4 v0 = p[0], v1 = p[1], v2 = p[2];
            s[0] += v0.x; s[1] += v0.y; s[2] += v0.z; s[3] += v0.w;
            s[4] += v1.x; s[5] += v1.y; s[6] += v1.z; s[7] += v1.w;
            s[8] += v2.x; s[9] += v2.y; s[10] += v2.z; s[11] += v2.w;
        }
#pragma unroll
        for (int c = 0; c < 12; ++c) red[c][tid] = s[c];
        __syncthreads();
        for (int st = 128; st > 0; st >>= 1) {
            if (tid < st) {
#pragma unroll
                for (int c = 0; c < 12; ++c) red[c][tid] += red[c][tid + st];
            }
            __syncthreads();
        }
        if (tid < 12) part[bx * 12 + tid] = red[tid][0];
        return;
    }
    if (bx < 144) {
        int i = (bx - 128) * 256 + tid;
        csums[i * 2] = 0.f;
        csums[i * 2 + 1] = 0.f;
        return;
    }
    if (bx < 160) {
        const int b = bx - 144;
        for (int k = tid; k < 512; k += 256) se[k] = swishf(te[b * 512 + k]);
        __syncthreads();
        float acc = tb[tid];
        for (int k = 0; k < 512; ++k) acc += se[k] * W[k * 256 + tid];
        t[b * 256 + tid] = acc;
        return;
    }
    const int r = bx - 160;
    const float* K = (r >> 7) ? K1 : K0;
    u16* kqp = (r >> 7) ? kqp1 : kqp0;
    const int o = r & 127;
    float s = 0.f, ss = 0.f;
    if (o < CC) {
        for (int idx = tid; idx < KTAPS; idx += 256) {
            float v = K[(size_t)idx * CC + o];
            s += v; ss += v * v;
        }
    }
    rs[tid] = s; rss[tid] = ss;
    __syncthreads();
    for (int st = 128; st > 0; st >>= 1) {
        if (tid < st) { rs[tid] += rs[tid + st]; rss[tid] += rss[tid + st]; }
        __syncthreads();
    }
    if (tid == 0) {
        float m = rs[0] * (1.f / KTAPS);
        float var = rss[0] * (1.f / KTAPS) - m * m;
        mb[0] = m;
        mb[1] = rsqrtf(var + 1e-5f);
    }
    __syncthreads();
    float m = mb[0], inv = mb[1];
    for (int idx = tid; idx < 1152; idx += 256) {
        int tap = idx >> 7, ic = idx & 127;
        float v = 0.f;
        if (o < CC && ic < CC) v = (K[((size_t)tap * CC + ic) * CC + o] - m) * inv;
        int step = tap * 8 + (ic >> 4);
        int lane2 = ((ic >> 3) & 1) * 32 + (o & 31);
        int j = ic & 7;
        kqp[(size_t)(step * 4 + (o >> 5)) * 512 + lane2 * 8 + j] = f2bf(v);
    }
}

// ---------------- MFMA 32x32x16 implicit-GEMM conv, 128px x 128oc, 512 threads ----
// R17 skeleton. MODE 0: hb==0 blocks compute circuit-1 (y1) post-epilogue.
// MODE 1: 2-barrier FiLM prologue (stats thread reads y1 direct from global);
// y2 circuit moved post-epilogue (hb==0 only). k_mid0 eliminated.
template <int MODE>
__launch_bounds__(512, 2)
__global__ void k_conv(const void* __restrict__ inp, const u16* __restrict__ kqp,
                       const float* __restrict__ bias, u16* __restrict__ outp,
                       float* __restrict__ csum,
                       const float* __restrict__ part, const float* __restrict__ csin,
                       const float* __restrict__ t, const float* __restrict__ gs,
                       const float* __restrict__ gb, const float* __restrict__ qp,
                       const float* __restrict__ y1in, float* __restrict__ yout) {
    __shared__ u16 As[32768];      // 64KB: 4 rows x 64 px x 128 ch (then repack)
    __shared__ float cfA[132], cfB[132];   // MODE1 coefs, stride-33 (conflict-free)
    __shared__ float pr_y1[12], pr_pin[12], pr_sst[8][2];
    const int hb = blockIdx.x, b = blockIdx.y;
    const int hp = ((hb & 7) << 2) | (hb >> 3);   // XCD band swizzle (bijective 0..31)
    const int h0 = hp * 2;
    const int tid = threadIdx.x, lane = tid & 63, wid = tid >> 6;
    const int wm = wid & 1, wn = wid >> 1;
    const int l31 = lane & 31;
    const int rr = tid >> 8, pp = (tid >> 2) & 63, ck = tid & 3;
    const int swz = (pp & 15) << 4;

    float fv[32]; short8 sv[4];
    float fv2[32]; short8 sv2[4];

#define LOADCHUNK(r, fvv, svv, val) do { \
    const int hi_ = h0 + (r) - 1; \
    val = (hi_ >= 0 && hi_ < 64); \
    if (val) { \
        const size_t px_ = (size_t)((b * 64 + hi_) * 64 + pp); \
        if (MODE == 0) { \
            const float* sp_ = (const float*)inp + px_ * 128 + 12 + ck * 32; \
            if (ck < 3) { \
                _Pragma("unroll") for (int j = 0; j < 8; ++j) *(float4*)&fvv[j * 4] = ((const float4*)sp_)[j]; \
            } else { \
                _Pragma("unroll") for (int j = 0; j < 5; ++j) *(float4*)&fvv[j * 4] = ((const float4*)sp_)[j]; \
                _Pragma("unroll") for (int e = 20; e < 32; ++e) fvv[e] = 0.f; \
            } \
        } else { \
            const u16* sp_ = (const u16*)inp + px_ * 128 + ck * 32; \
            _Pragma("unroll") for (int k = 0; k < 4; ++k) svv[k] = ((const short8*)sp_)[k]; \
        } \
    } \
} while (0)

#define WRITECHUNK(r, fvv, svv, val) do { \
    u16 t_[32]; \
    if (val) { \
        if (MODE == 0) { \
            _Pragma("unroll") for (int e = 0; e < 32; ++e) t_[e] = f2bf(fvv[e]); \
        } else { \
            _Pragma("unroll") for (int e = 0; e < 32; ++e) { \
                int c_ = ck * 32 + e; \
                float f_ = bf2f((u16)svv[e >> 3][e & 7]); \
                float w_ = swishf(f_ * cfA[ck * 33 + e] + cfB[ck * 33 + e]); \
                t_[e] = (c_ < CC) ? f2bf(w_) : (u16)0; \
            } \
        } \
    } else { \
        _Pragma("unroll") for (int e = 0; e < 32; ++e) t_[e] = 0; \
    } \
    char* rb_ = (char*)As + ((r) * 64 + pp) * 256; \
    _Pragma("unroll") for (int k = 0; k < 4; ++k) \
        *(short8*)(rb_ + ((ck * 64 + k * 16) ^ swz)) = *(const short8*)&t_[k * 8]; \
} while (0)

    bool valA, valC;
    if (MODE == 1) {
        // issue all staging loads first; prologue math hides under their latency
        LOADCHUNK(rr, fv, sv, valA);
        LOADCHUNK(2 + rr, fv2, sv2, valC);

        // ---- 2-barrier FiLM prologue (y1 precomputed by conv0) ----
        if (tid < 12) pr_y1[tid] = y1in[b * 12 + tid];
        if (tid >= 64 && tid < 72) {          // stats on a different wave
            const int g = tid - 64;
            float S = 0.f, SS = 0.f;
#pragma unroll
            for (int e = 0; e < 16; ++e) {
                int orig = g * 16 + e;
                if (orig >= 12) {
                    int cc = orig - 12;
                    S += csin[(b * 128 + cc) * 2];
                    SS += csin[(b * 128 + cc) * 2 + 1];
                }
            }
            if (g == 0) {
#pragma unroll
                for (int c = 0; c < 12; ++c) {
                    float v = y1in[b * 12 + c];   // direct global read (no LDS dep)
                    S += 4096.f * v;
                    SS += 4096.f * v * v;
                }
            }
            float mu = S * (1.f / 65536.f);
            float var = SS * (1.f / 65536.f) - mu * mu;
            pr_sst[g][0] = mu;
            pr_sst[g][1] = rsqrtf(var + 1e-6f);
        }
        __syncthreads();
        if (tid < 128) {
            const int chn = tid, g = chn >> 4;
            float mu = pr_sst[g][0], isd = pr_sst[g][1];
            float a = isd * gs[chn];
            float bb = gb[chn] - mu * a;
            float sc = t[b * 256 + chn], sh = t[b * 256 + 128 + chn];
            float Af = a * (1.f + sc);
            float Bf = bb * (1.f + sc) + sh;
            if (chn >= 12) {
                int cc = chn - 12;
                cfA[(cc >> 5) * 33 + (cc & 31)] = Af;
                cfB[(cc >> 5) * 33 + (cc & 31)] = Bf;
            } else {
                pr_pin[chn] = swishf(pr_y1[chn] * Af + Bf);
            }
        }
        __syncthreads();                  // cf + pin visible
        WRITECHUNK(rr, fv, sv, valA);
    } else {
        LOADCHUNK(rr, fv, sv, valA);
        WRITECHUNK(rr, fv, sv, valA);
        LOADCHUNK(2 + rr, fv2, sv2, valC);   // lands under the p=0 phase
    }

    // B prologue: ring depth 4, one 32-oc fragment per wave per step
    const u16* bp = kqp + (size_t)wn * 512 + (size_t)lane * 8;
    short8 breg[4];
#pragma unroll
    for (int s = 0; s < 4; ++s) breg[s] = *(const short8*)(bp + ((size_t)s << 11));

    // A-frag addressing (static arrays, compile-time indexed)
    const int kh16 = (lane >> 5) << 4;
    int coloff[2][3], colswz[2][3];
#pragma unroll
    for (int mf = 0; mf < 2; ++mf)
#pragma unroll
        for (int q = 0; q < 3; ++q) {
            int c = mf * 32 + l31 + q - 1;
            int cc = c < 0 ? 0 : (c > 63 ? 63 : c);
            coloff[mf][q] = cc << 7;
            colswz[mf][q] = (cc & 15) << 4;
        }
    const bool e0 = (l31 == 0), e1 = (l31 == 31);
    const short8 zero8 = {0, 0, 0, 0, 0, 0, 0, 0};
    const int rowb = wm * 8192;

    asm volatile("s_waitcnt lgkmcnt(0)" ::: "memory");
    __builtin_amdgcn_s_barrier();         // raw: phase-C vmcnt stays outstanding

    f32x16 acc[2];
#pragma unroll
    for (int mf = 0; mf < 2; ++mf)
#pragma unroll
        for (int r = 0; r < 16; ++r) acc[mf][r] = 0.f;

#define AREAD(dst, s) do { \
    const int tap_ = (s) >> 3, p_ = tap_ / 3, q_ = tap_ % 3; \
    const int chb_ = ((s) & 7) << 5; \
    dst[0] = *(const short8*)&As[rowb + p_ * 8192 + coloff[0][q_] + (((chb_ + kh16) ^ colswz[0][q_]) >> 1)]; \
    dst[1] = *(const short8*)&As[rowb + p_ * 8192 + coloff[1][q_] + (((chb_ + kh16) ^ colswz[1][q_]) >> 1)]; \
} while (0)

#define STEP(s, base, lim) do { \
    const int cur_ = ((s) - (base)) & 1, nxt_ = cur_ ^ 1; \
    if ((s) + 1 < (lim)) AREAD(afr[nxt_], (s) + 1); \
    const int q_ = ((s) >> 3) % 3; \
    short8 a0_ = afr[cur_][0], a1_ = afr[cur_][1]; \
    if (q_ == 0) a0_ = e0 ? zero8 : a0_; \
    if (q_ == 2) a1_ = e1 ? zero8 : a1_; \
    __builtin_amdgcn_s_setprio(1); \
    acc[0] = __builtin_amdgcn_mfma_f32_32x32x16_bf16(a0_, breg[(s) & 3], acc[0], 0, 0, 0); \
    acc[1] = __builtin_amdgcn_mfma_f32_32x32x16_bf16(a1_, breg[(s) & 3], acc[1], 0, 0, 0); \
    __builtin_amdgcn_s_setprio(0); \
    if ((s) + 4 < 72) breg[(s) & 3] = *(const short8*)(bp + ((size_t)((s) + 4) << 11)); \
} while (0)

    short8 afr[2][2];
    AREAD(afr[0], 0);
#pragma unroll
    for (int s = 0; s < 24; ++s) STEP(s, 0, 24);     // p=0 taps (LDS rows wm..wm+1)

    WRITECHUNK(2 + rr, fv2, sv2, valC);              // loads arrived during p=0
    asm volatile("s_waitcnt lgkmcnt(0)" ::: "memory");
    __builtin_amdgcn_s_barrier();

    AREAD(afr[0], 24);
#pragma unroll
    for (int s = 24; s < 72; ++s) STEP(s, 24, 72);   // p=1,2 taps

    // ---- epilogue: bias, csum, LDS repack -> coalesced bf16 stores ----
    const int oc = wn * 32 + l31;
    const float bv = (oc < CC) ? bias[oc] : 0.f;
    float cs = 0.f, cq = 0.f;
    const int rbase = (lane >> 5) << 2;

    asm volatile("s_waitcnt lgkmcnt(0)" ::: "memory");
    __builtin_amdgcn_s_barrier();                    // all AREADs done; reuse As
#pragma unroll
    for (int mf = 0; mf < 2; ++mf) {
#pragma unroll
        for (int r = 0; r < 16; ++r) {
            int drow = (r & 3) + ((r >> 2) << 3) + rbase;
            int flat = wm * 64 + mf * 32 + drow;     // 0..127 within tile
            float v = acc[mf][r] + bv;
            As[flat * 128 + oc] = f2bf(v);
            cs += v;
            cq += v * v;
        }
    }
    asm volatile("s_waitcnt lgkmcnt(0)" ::: "memory");
    __builtin_amdgcn_s_barrier();
    {
        size_t obase = (size_t)(b * 4096 + h0 * 64) * 128;
#pragma unroll
        for (int k = 0; k < 4; ++k)
            *(short8*)&outp[obase + k * 4096 + tid * 8] = *(const short8*)&As[k * 4096 + tid * 8];
    }
    cs += __shfl_xor(cs, 32);
    cq += __shfl_xor(cq, 32);
    if (lane < 32) {
        atomicAdd(&csum[(b * 128 + oc) * 2], cs);
        atomicAdd(&csum[(b * 128 + oc) * 2 + 1], cq);
    }

    // ---- post-epilogue circuits (hb==0 blocks only, off the critical path) ----
    if (MODE == 0 && hb == 0) {
        __syncthreads();
        if (tid < 12) {
            float s = 0.f;
#pragma unroll
            for (int k = 0; k < 8; ++k) s += part[(b * 8 + k) * 12 + tid];
            pr_y1[tid] = s * (1.f / 4096.f);
        }
        __syncthreads();
        if (tid < 3) {
            float z[4];
            run_circuit(&pr_y1[tid * 4], qp + tid * 4, z);
#pragma unroll
            for (int w = 0; w < 4; ++w) yout[b * 12 + tid * 4 + w] = z[w];
        }
    }
    if (MODE == 1 && hb == 0) {
        if (tid < 3) {                    // pr_pin persisted in LDS since prologue
            float z[4];
            run_circuit(&pr_pin[tid * 4], qp + tid * 4, z);
#pragma unroll
            for (int w = 0; w < 4; ++w) yout[b * 12 + tid * 4 + w] = z[w];
        }
    }
#undef LOADCHUNK
#undef WRITECHUNK
#undef AREAD
#undef STEP
}

// ---------------- fused: GN1 stats + coefs + quantum output ----------------
__global__ void k_mid1(const float* __restrict__ csum, const float* __restrict__ y2,
                       const float* __restrict__ gs, const float* __restrict__ gb,
                       float* __restrict__ A2, float* __restrict__ B2,
                       float* __restrict__ oq) {
    __shared__ float sst[128][2];
    int tid = threadIdx.x;
    if (tid < 128) {
        int b = tid >> 3, g = tid & 7;
        float S = 0.f, SS = 0.f;
#pragma unroll
        for (int e = 0; e < 16; ++e) {
            int orig = g * 16 + e;
            if (orig >= 12) {
                int cc = orig - 12;
                S += csum[(b * 128 + cc) * 2];
                SS += csum[(b * 128 + cc) * 2 + 1];
            }
        }
        if (g == 0) {
#pragma unroll
            for (int c = 0; c < 12; ++c) {
                float v = y2[b * 12 + c];
                S += 4096.f * v;
                SS += 4096.f * v * v;
            }
        }
        float mu = S * (1.f / 65536.f);
        float var = SS * (1.f / 65536.f) - mu * mu;
        sst[tid][0] = mu;
        sst[tid][1] = rsqrtf(var + 1e-6f);
    }
    __syncthreads();
    for (int i = tid; i < 2048; i += 256) {
        int b = i >> 7, c = i & 127, g = c >> 4;
        float mu = sst[b * 8 + g][0], isd = sst[b * 8 + g][1];
        float a = isd * gs[c];
        A2[i] = a;
        B2[i] = gb[c] - mu * a;
    }
    if (tid < 192) {
        int b = tid / 12, c = tid % 12;
        float mu = sst[b * 8][0], isd = sst[b * 8][1];
        float a = isd * gs[c];
        float bb = gb[c] - mu * a;
        oq[b * 12 + c] = swishf(y2[b * 12 + c] * a + bb);
    }
}

// ---------------- out = x + swish(A2*v + B2) ----------------
__global__ void k_final(const float* __restrict__ x, const u16* __restrict__ co,
                        const float* __restrict__ A2, const float* __restrict__ B2,
                        const float* __restrict__ oq, float* __restrict__ outp) {
    const int t = blockIdx.x, b = blockIdx.y;
    const int seg = t >> 6, hraw = t & 63;
    const int h = ((hraw & 7) << 3) | (hraw >> 3);
    const int tid = threadIdx.x;
    const size_t px = (size_t)(b * 64 + h) * 64 + seg * 8 + (tid >> 5);
    const int c4 = tid & 31, c = c4 * 4;
    float4 xv = *(const float4*)(x + px * CDIM + c);
    float4 r;
    if (c4 < 3) {
        const float* q = oq + b * 12 + c;
        r.x = xv.x + q[0]; r.y = xv.y + q[1]; r.z = xv.z + q[2]; r.w = xv.w + q[3];
    } else {
        int cc = c - 12;
        const u16* hp = co + px * 128 + cc;
        float4 a = *(const float4*)(A2 + b * 128 + c);
        float4 bb = *(const float4*)(B2 + b * 128 + c);
        r.x = xv.x + swishf(bf2f(hp[0]) * a.x + bb.x);
        r.y = xv.y + swishf(bf2f(hp[1]) * a.y + bb.y);
        r.z = xv.z + swishf(bf2f(hp[2]) * a.z + bb.z);
        r.w = xv.w + swishf(bf2f(hp[3]) * a.w + bb.w);
    }
    *(float4*)(outp + px * CDIM + c) = r;
}

extern "C" void kernel_launch(void* const* d_in, const int* in_sizes, int n_in,
                              void* d_out, int out_size, void* d_ws, size_t ws_size,
                              hipStream_t stream) {
    const float* x        = (const float*)d_in[0];
    const float* time_emb = (const float*)d_in[1];
    const float* qparams  = (const float*)d_in[2];
    const float* c0k      = (const float*)d_in[3];
    const float* c0b      = (const float*)d_in[4];
    const float* c1k      = (const float*)d_in[5];
    const float* c1b      = (const float*)d_in[6];
    const float* g0s      = (const float*)d_in[7];
    const float* g0b      = (const float*)d_in[8];
    const float* g1s      = (const float*)d_in[9];
    const float* g1b      = (const float*)d_in[10];
    const float* tw       = (const float*)d_in[11];
    const float* tb       = (const float*)d_in[12];
    float* outp = (float*)d_out;
    float* ws = (float*)d_ws;

    size_t o = 0;
    auto alloc = [&](size_t n) { size_t r = o; o += (n + 15) & ~(size_t)15; return r; };
    float* part   = ws + alloc(1536);
    float* csums  = ws + alloc(8192);            // csum0 | csum1
    float* csum0  = csums;
    float* csum1  = csums + 4096;
    float* t      = ws + alloc(4096);
    float* A2     = ws + alloc(2048);
    float* B2     = ws + alloc(2048);
    float* y1     = ws + alloc(192);
    float* y2     = ws + alloc(192);
    float* oq     = ws + alloc(192);
    u16* kqp0     = (u16*)(ws + alloc(73728));   // 72*4*512 bf16
    u16* kqp1     = (u16*)(ws + alloc(73728));
    u16* convA    = (u16*)(ws + alloc(4194304)); // [16][4096][128] bf16 (conv0 out)
    u16* convB    = (u16*)(ws + alloc(4194304)); // conv1 out

    k_misc<<<416, 256, 0, stream>>>(x, part, csums, time_emb, tw, tb, t,
                                    c0k, c1k, kqp0, kqp1);

    dim3 cgrid(32, 16);
    k_conv<0><<<cgrid, 512, 0, stream>>>(x, kqp0, c0b, convA, csum0,
                                         part, nullptr, nullptr, nullptr,
                                         nullptr, qparams, nullptr, y1);
    k_conv<1><<<cgrid, 512, 0, stream>>>(convA, kqp1, c1b, convB, csum1,
                                         nullptr, csum0, t, g0s, g0b, qparams, y1, y2);
    k_mid1<<<1, 256, 0, stream>>>(csum1, y2, g1s, g1b, A2, B2, oq);
    k_final<<<dim3(512, 16), 256, 0, stream>>>(x, convB, A2, B2, oq, outp);
}